// Round 2
// baseline (626.568 us; speedup 1.0000x reference)
//
#include <hip/hip_runtime.h>

#define NB 4096

typedef __attribute__((ext_vector_type(8)))  __bf16 bf16x8;
typedef __attribute__((ext_vector_type(4)))  float  f32x4;
typedef __attribute__((ext_vector_type(16))) float  f32x16;

__device__ __forceinline__ float gelu_fast(float x){
    float x2 = x * x;
    float y  = x * (0.79788456f + 0.03567741f * x2);
    float e  = __expf(2.0f * y);
    float t  = 1.0f - 2.0f / (e + 1.0f);
    return 0.5f * x * (1.0f + t);
}
__device__ __forceinline__ unsigned short f2bf(float x){
    unsigned b = __float_as_uint(x);
    b += 0x7fffu + ((b >> 16) & 1u);
    return (unsigned short)(b >> 16);
}

// ---------------- pack offsets (elements) ----------------
#define O_WP0  0
#define O_WP1  40960
#define O_WP2  368640
#define O_PROJ 696320
#define O_VAL1 761856
#define O_POS1 827392
#define O_RES1 892928
#define O_VAL2 958464
#define O_RES2 991232
#define O_POS2 1515520
#define O_MIX  1519616
#define PK_TOTAL 1523712

__device__ __forceinline__ unsigned short pack_std_elem(const float* W, int N, int t){
    int j = t & 7, lane = (t >> 3) & 63, rest = t >> 9;
    int ntcnt = N >> 4;
    int nt = rest % ntcnt, kk = rest / ntcnt;
    int n = nt*16 + (lane & 15), k = kk*32 + ((lane >> 4) << 3) + j;
    return f2bf(W[k * N + n]);
}
__device__ __forceinline__ unsigned short pack_pad_elem(const float* W, int Nreal, int t){
    int j = t & 7, lane = (t >> 3) & 63, kk = t >> 9;
    int n = lane & 15, k = kk*32 + ((lane >> 4) << 3) + j;
    return (n < Nreal) ? f2bf(W[k * Nreal + n]) : (unsigned short)0;
}

// conv sections packed for mfma_32x32x16: B[k][n], n = nt*32 + (lane&31),
// k_local = (lane>>5)*8 + j, K order = tap-major, 16-chan chunks inner.
__global__ __launch_bounds__(256) void pack_weights(
    const float* __restrict__ W0, const float* __restrict__ W1, const float* __restrict__ W2,
    const float* __restrict__ proj_w, const float* __restrict__ val_w1,
    const float* __restrict__ pos_w1, const float* __restrict__ res_w1,
    const float* __restrict__ val_w2, const float* __restrict__ res_w2,
    const float* __restrict__ pos_w2, const float* __restrict__ mix_w,
    unsigned short* __restrict__ pk)
{
    int idx = blockIdx.x * 256 + threadIdx.x;
    if (idx >= PK_TOTAL) return;
    if (idx < O_WP1){
        int t = idx;
        int j = t & 7, lane = (t >> 3) & 63, nt = (t >> 9) & 7, s = t >> 12;   // s 0..9
        int co = nt*32 + (lane & 31);
        int tap = s >> 1, ci = ((s & 1) << 4) + ((lane >> 5) << 3) + j;
        pk[idx] = f2bf(W0[co*160 + ci*5 + tap]);
    } else if (idx < O_WP2){
        int t = idx - O_WP1;
        int j = t & 7, lane = (t >> 3) & 63, nt = (t >> 9) & 7, s = t >> 12;   // s 0..79
        int co = nt*32 + (lane & 31);
        int tap = s >> 4, ci = ((s & 15) << 4) + ((lane >> 5) << 3) + j;
        pk[idx] = f2bf(W1[co*1280 + ci*5 + tap]);
    } else if (idx < O_PROJ){
        int t = idx - O_WP2;
        int j = t & 7, lane = (t >> 3) & 63, nt = (t >> 9) & 7, s = t >> 12;   // s 0..79
        int co = nt*32 + (lane & 31);
        int tap = s >> 4, ci = ((s & 15) << 4) + ((lane >> 5) << 3) + j;
        pk[idx] = f2bf(W2[co*1280 + ci*5 + tap]);
    }
    else if (idx < O_VAL1) pk[idx] = pack_std_elem(proj_w, 256, idx - O_PROJ);
    else if (idx < O_POS1) pk[idx] = pack_std_elem(val_w1, 256, idx - O_VAL1);
    else if (idx < O_RES1) pk[idx] = pack_std_elem(pos_w1, 256, idx - O_POS1);
    else if (idx < O_VAL2) pk[idx] = pack_std_elem(res_w1, 256, idx - O_RES1);
    else if (idx < O_RES2) pk[idx] = pack_std_elem(val_w2, 128, idx - O_VAL2);
    else if (idx < O_POS2) pk[idx] = pack_std_elem(res_w2, 2048, idx - O_RES2);
    else if (idx < O_MIX)  pk[idx] = pack_pad_elem(pos_w2, 4, idx - O_POS2);
    else                   pk[idx] = pack_pad_elem(mix_w, 2, idx - O_MIX);
}

// ---------------- Kernel 1: 32x32x16 MFMA conv, 1 batch/block, 3 blocks/CU ----------------
// LDS: ht 68*264*2 = 35904 B + xt 68*40*2 = 5440 B = 41344 B -> 3 blocks/CU
#define HT_S 264
#define XT_S 40

__global__ __launch_bounds__(256, 3) void conv_mfma_kernel(
    const float* __restrict__ A,
    const float* __restrict__ B0, const float* __restrict__ B1, const float* __restrict__ B2,
    const unsigned short* __restrict__ wp0, const unsigned short* __restrict__ wp1,
    const unsigned short* __restrict__ wp2,
    unsigned short* __restrict__ pooled)
{
    __shared__ __align__(16) unsigned short xt[68 * XT_S];
    __shared__ __align__(16) unsigned short ht[68 * HT_S];

    const int tid  = threadIdx.x;
    const int b    = blockIdx.x;
    const int w    = tid >> 6;
    const int lane = tid & 63;
    const int l31  = lane & 31;
    const int hi   = lane >> 5;
    const int hi8  = hi << 3;
    const int w2   = w << 1;

    for (int i = tid; i < 4 * HT_S; i += 256){
        int r = i / HT_S, c = i - r * HT_S;
        int rr = (r < 2 ? r : r + 64);
        ht[rr * HT_S + c] = 0;
    }
    if (tid < 128){
        int r = tid >> 5, c = tid & 31;
        int rr = (r < 2 ? r : r + 64);
        xt[rr * XT_S + c] = 0;
    }
    {
        const float* Ab = A + (size_t)b * 2048;
        int e0 = tid << 3;
        int t = e0 >> 5, c = e0 & 31;
        const float4* p = (const float4*)(Ab + e0);
        float4 v0 = p[0], v1 = p[1];
        union { unsigned short u[8]; bf16x8 v; } pkv;
        pkv.u[0]=f2bf(v0.x); pkv.u[1]=f2bf(v0.y); pkv.u[2]=f2bf(v0.z); pkv.u[3]=f2bf(v0.w);
        pkv.u[4]=f2bf(v1.x); pkv.u[5]=f2bf(v1.y); pkv.u[6]=f2bf(v1.z); pkv.u[7]=f2bf(v1.w);
        *(bf16x8*)&xt[(t + 2) * XT_S + c] = pkv.v;
    }
    __syncthreads();

    f32x16 acc[2][2];

#define ZERO32 \
    { _Pragma("unroll") for (int mt = 0; mt < 2; ++mt) \
      _Pragma("unroll") for (int nt = 0; nt < 2; ++nt) \
      _Pragma("unroll") for (int r = 0; r < 16; ++r) acc[mt][nt][r] = 0.f; }
// A fragment: row = mt*32 + (lane&31) + tap, k-chans = cichunk*16 + (lane>>5)*8 .. +8
#define LOADA_H32(BUF, S) \
    { _Pragma("unroll") for (int mt = 0; mt < 2; ++mt) \
          BUF[mt] = *(const bf16x8*)&ht[((mt << 5) + l31 + ((S) >> 4)) * HT_S + (((S) & 15) << 4) + hi8]; }
#define LOADA_X32(BUF, S) \
    { _Pragma("unroll") for (int mt = 0; mt < 2; ++mt) \
          BUF[mt] = *(const bf16x8*)&xt[((mt << 5) + l31 + ((S) >> 1)) * XT_S + (((S) & 1) << 4) + hi8]; }
#define LOADB32(BUF, S, WP) \
    { _Pragma("unroll") for (int nt = 0; nt < 2; ++nt) \
          BUF[nt] = *(const bf16x8*)((WP) + ((size_t)((((S) << 3) + w2 + nt) << 6) + lane) * 8); }
#define MF32(AB, BB_) \
    { _Pragma("unroll") for (int mt = 0; mt < 2; ++mt) \
      _Pragma("unroll") for (int nt = 0; nt < 2; ++nt) \
          acc[mt][nt] = __builtin_amdgcn_mfma_f32_32x32x16_bf16(AB[mt], BB_[nt], acc[mt][nt], 0, 0, 0); }
// C/D: col = lane&31, row = (r&3) + 8*(r>>2) + 4*(lane>>5)  [m74/m101]
#define EPI32(BIAS) \
    { float bvn[2]; \
      _Pragma("unroll") for (int nt = 0; nt < 2; ++nt) bvn[nt] = (BIAS)[((w2 + nt) << 5) + l31]; \
      _Pragma("unroll") for (int mt = 0; mt < 2; ++mt) \
      _Pragma("unroll") for (int nt = 0; nt < 2; ++nt) \
      _Pragma("unroll") for (int r = 0; r < 16; ++r){ \
          int row = (mt << 5) + (r & 3) + ((r >> 2) << 3) + (hi << 2) + 2; \
          float v = gelu_fast(acc[mt][nt][r] + bvn[nt]); \
          ht[row * HT_S + ((w2 + nt) << 5) + l31] = f2bf(v); } }

// depth-3 pipelined K-loop: each load issued ~8 MFMAs (~310 SIMD-cyc) before use
#define CONV_LAYER32(WP) \
    { bf16x8 Ba[2], Bb[2], Bc[2], Aa[2], Ab_[2], Ac[2]; \
      LOADB32(Ba, 0, WP); LOADA_H32(Aa, 0); \
      LOADB32(Bb, 1, WP); LOADA_H32(Ab_, 1); \
      LOADB32(Bc, 2, WP); LOADA_H32(Ac, 2); \
      for (int s = 0; s < 73; s += 3){ \
          MF32(Aa, Ba);  LOADB32(Ba, s + 3, WP); LOADA_H32(Aa, s + 3); \
          MF32(Ab_, Bb); LOADB32(Bb, s + 4, WP); LOADA_H32(Ab_, s + 4); \
          MF32(Ac, Bc);  LOADB32(Bc, s + 5, WP); LOADA_H32(Ac, s + 5); \
      } \
      MF32(Aa, Ba);  LOADB32(Ba, 78, WP); LOADA_H32(Aa, 78); \
      MF32(Ab_, Bb); LOADB32(Bb, 79, WP); LOADA_H32(Ab_, 79); \
      MF32(Ac, Bc); \
      MF32(Aa, Ba); \
      MF32(Ab_, Bb); }

    // ---- conv0 (K=160: 10 k-steps), depth-2 pipeline ----
    ZERO32;
    {
        bf16x8 Ba[2], Bb[2], Aa[2], Ab_[2];
        LOADB32(Ba, 0, wp0); LOADA_X32(Aa, 0);
        LOADB32(Bb, 1, wp0); LOADA_X32(Ab_, 1);
        for (int s = 0; s < 6; s += 2){
            MF32(Aa, Ba);  LOADB32(Ba, s + 2, wp0); LOADA_X32(Aa, s + 2);
            MF32(Ab_, Bb); LOADB32(Bb, s + 3, wp0); LOADA_X32(Ab_, s + 3);
        }
        MF32(Aa, Ba);  LOADB32(Ba, 8, wp0); LOADA_X32(Aa, 8);
        MF32(Ab_, Bb); LOADB32(Bb, 9, wp0); LOADA_X32(Ab_, 9);
        MF32(Aa, Ba);
        MF32(Ab_, Bb);
    }
    EPI32(B0);
    __syncthreads();

    // ---- conv1 ----
    ZERO32;
    CONV_LAYER32(wp1);
    __syncthreads();
    EPI32(B1);
    __syncthreads();

    // ---- conv2 + mean pool ----
    ZERO32;
    CONV_LAYER32(wp2);
    {
        float bvn[2];
        #pragma unroll
        for (int nt = 0; nt < 2; ++nt) bvn[nt] = B2[((w2 + nt) << 5) + l31];
        float s0[2];
        #pragma unroll
        for (int nt = 0; nt < 2; ++nt){
            float a = 0.f;
            #pragma unroll
            for (int mt = 0; mt < 2; ++mt)
                #pragma unroll
                for (int r = 0; r < 16; ++r)
                    a += gelu_fast(acc[mt][nt][r] + bvn[nt]);
            s0[nt] = a;
        }
        #pragma unroll
        for (int nt = 0; nt < 2; ++nt) s0[nt] += __shfl_xor(s0[nt], 32);
        if (hi == 0){
            #pragma unroll
            for (int nt = 0; nt < 2; ++nt)
                pooled[(size_t)b * 256 + ((w2 + nt) << 5) + l31] = f2bf(s0[nt] * (1.0f / 64.0f));
        }
    }
}

// ---------------- Kernel 2a: heads stages A-C, 16 batches/block ----------------
#define AS 264

__global__ __launch_bounds__(256) void heads_a_kernel(
    const unsigned short* __restrict__ pooled,
    const float* __restrict__ proj_b, const float* __restrict__ val_b1,
    const float* __restrict__ pos_b1, const float* __restrict__ res_b1,
    const float* __restrict__ val_b2, const float* __restrict__ pos_b2,
    const float* __restrict__ mix_b,
    const unsigned short* __restrict__ pk,
    unsigned short* __restrict__ rh, float* __restrict__ meta,
    float* __restrict__ accums)
{
    __shared__ unsigned short pb [16 * AS];
    __shared__ unsigned short eb [16 * AS];
    __shared__ unsigned short vb [16 * AS];
    __shared__ unsigned short phb[16 * AS];
    __shared__ unsigned short rhb[16 * AS];
    __shared__ float av [16 * 132];
    __shared__ float avs[16 * 132];
    __shared__ float psort[16][4];
    __shared__ int   rank [16][4];
    __shared__ float qsh  [16][2];
    __shared__ float mlsh [16][2];
    __shared__ float sposh[16][4];

    const int tid  = threadIdx.x;
    const int b0   = blockIdx.x * 16;
    const int w    = tid >> 6;
    const int lane = tid & 63;
    const int l15  = lane & 15;
    const int q    = lane >> 4;
    const int q8   = q << 3;
    const int q4   = q << 2;

    {
        int g = tid >> 4, seg = tid & 15;
        const unsigned short* ps = pooled + ((size_t)(b0 + g) << 8) + (seg << 4);
        bf16x8 a0 = *(const bf16x8*)ps;
        bf16x8 a1 = *(const bf16x8*)(ps + 8);
        *(bf16x8*)&pb[g * AS + (seg << 4)]     = a0;
        *(bf16x8*)&pb[g * AS + (seg << 4) + 8] = a1;
    }
    __syncthreads();

#define HGEMM256(ASRC, GOFF, BIAS, DST) \
    { f32x4 hacc[4]; \
      _Pragma("unroll") for (int nt = 0; nt < 4; ++nt) hacc[nt] = (f32x4){0.f,0.f,0.f,0.f}; \
      _Pragma("unroll") for (int kk = 0; kk < 8; ++kk){ \
          bf16x8 af = *(const bf16x8*)&(ASRC)[l15 * AS + (kk << 5) + q8]; \
          _Pragma("unroll") for (int nt = 0; nt < 4; ++nt){ \
              bf16x8 bfr = *(const bf16x8*)(pk + (GOFF) + (size_t)((((kk << 4) + (w << 2) + nt) << 6) + lane) * 8); \
              hacc[nt] = __builtin_amdgcn_mfma_f32_16x16x32_bf16(af, bfr, hacc[nt], 0, 0, 0); } } \
      _Pragma("unroll") for (int nt = 0; nt < 4; ++nt){ \
          int n = (w << 6) + (nt << 4) + l15; \
          float bv = (BIAS)[n]; \
          _Pragma("unroll") for (int r = 0; r < 4; ++r) \
              (DST)[(q4 + r) * AS + n] = f2bf(gelu_fast(hacc[nt][r] + bv)); } }

    HGEMM256(pb, O_PROJ, proj_b, eb);
    __syncthreads();

    HGEMM256(eb, O_VAL1, val_b1, vb);
    HGEMM256(eb, O_POS1, pos_b1, phb);
    HGEMM256(eb, O_RES1, res_b1, rhb);
    __syncthreads();

    {
        f32x4 acc2[2];
        #pragma unroll
        for (int nt = 0; nt < 2; ++nt) acc2[nt] = (f32x4){0.f,0.f,0.f,0.f};
        #pragma unroll
        for (int kk = 0; kk < 8; ++kk){
            bf16x8 af = *(const bf16x8*)&vb[l15 * AS + (kk << 5) + q8];
            #pragma unroll
            for (int nt = 0; nt < 2; ++nt){
                bf16x8 bfr = *(const bf16x8*)(pk + O_VAL2 + (size_t)(((kk*8 + w*2 + nt) << 6) + lane) * 8);
                acc2[nt] = __builtin_amdgcn_mfma_f32_16x16x32_bf16(af, bfr, acc2[nt], 0, 0, 0);
            }
        }
        #pragma unroll
        for (int nt = 0; nt < 2; ++nt){
            int j = (w << 5) + (nt << 4) + l15;
            float bv = val_b2[j];
            #pragma unroll
            for (int r = 0; r < 4; ++r)
                av[(q4 + r) * 132 + j] = acc2[nt][r] + bv;
        }
    }
    if (w == 0){
        f32x4 accp = (f32x4){0.f,0.f,0.f,0.f};
        #pragma unroll
        for (int kk = 0; kk < 8; ++kk){
            bf16x8 af  = *(const bf16x8*)&phb[l15 * AS + (kk << 5) + q8];
            bf16x8 bfr = *(const bf16x8*)(pk + O_POS2 + (size_t)((kk << 6) + lane) * 8);
            accp = __builtin_amdgcn_mfma_f32_16x16x32_bf16(af, bfr, accp, 0, 0, 0);
        }
        if (l15 < 4){
            float bv = pos_b2[l15];
            #pragma unroll
            for (int r = 0; r < 4; ++r){
                float raw = accp[r] + bv;
                sposh[q4 + r][l15] = 63.0f / (1.0f + __expf(-raw));
            }
        }
    } else if (w == 1){
        f32x4 accm = (f32x4){0.f,0.f,0.f,0.f};
        #pragma unroll
        for (int kk = 0; kk < 8; ++kk){
            bf16x8 af  = *(const bf16x8*)&eb[l15 * AS + (kk << 5) + q8];
            bf16x8 bfr = *(const bf16x8*)(pk + O_MIX + (size_t)((kk << 6) + lane) * 8);
            accm = __builtin_amdgcn_mfma_f32_16x16x32_bf16(af, bfr, accm, 0, 0, 0);
        }
        if (l15 < 2){
            #pragma unroll
            for (int r = 0; r < 4; ++r)
                mlsh[q4 + r][l15] = accm[r] + mix_b[l15];
        }
    }
    __syncthreads();

    if (tid < 16){
        int g = tid;
        float sv[4] = { sposh[g][0], sposh[g][1], sposh[g][2], sposh[g][3] };
        #pragma unroll
        for (int i = 0; i < 4; ++i){
            int r = 0;
            #pragma unroll
            for (int jj = 0; jj < 4; ++jj){
                r += (sv[jj] < sv[i]) ? 1 : 0;
                if (jj < i) r += (sv[jj] == sv[i]) ? 1 : 0;
            }
            rank[g][i] = r;
            psort[g][r] = sv[i];
        }
        psort[g][0] = 0.0f; psort[g][3] = 63.0f;
        float p1 = psort[g][1], p2 = psort[g][2];
        float g1 = p1, g2 = p2 - p1, g3 = 63.0f - p2;
        const float MG = 10.5f;
        float r1 = fmaxf(MG - g1, 0.f), r2 = fmaxf(MG - g2, 0.f), r3 = fmaxf(MG - g3, 0.f);
        float sp = (r1*r1 + r2*r2 + r3*r3) * (1.0f / 3.0f);
        float l0 = mlsh[g][0], l1 = mlsh[g][1];
        float m = fmaxf(l0, l1);
        float e0 = __expf(l0 - m), e1 = __expf(l1 - m);
        float inv = 1.0f / (e0 + e1);
        float q0 = e0 * inv, q1 = e1 * inv;
        qsh[g][0] = q0; qsh[g][1] = q1;
        float entc = q0 * logf(q0 + 1e-8f) + q1 * logf(q1 + 1e-8f);
        atomicAdd(&accums[2], entc);
        atomicAdd(&accums[3], q0);
        atomicAdd(&accums[4], q1);
        atomicAdd(&accums[5], sp);
    }
    __syncthreads();

    #pragma unroll
    for (int u2 = 0; u2 < 8; ++u2){
        int idx2 = tid * 8 + u2;
        int g = idx2 >> 7, j = idx2 & 127;
        avs[g * 132 + rank[g][j >> 5] * 32 + (j & 31)] = av[g * 132 + j];
    }
    __syncthreads();

    {
        int g = tid >> 4, c16 = (tid & 15) << 4;
        bf16x8 a0 = *(const bf16x8*)&rhb[g * AS + c16];
        bf16x8 a1 = *(const bf16x8*)&rhb[g * AS + c16 + 8];
        unsigned short* dst = rh + ((size_t)(b0 + g) << 8) + c16;
        *(bf16x8*)dst       = a0;
        *(bf16x8*)(dst + 8) = a1;
    }
    if (tid < 132){
        for (int g = 0; g < 16; ++g){
            float v;
            if (tid < 128)       v = avs[g * 132 + tid];
            else if (tid == 128) v = psort[g][1];
            else if (tid == 129) v = psort[g][2];
            else if (tid == 130) v = qsh[g][0];
            else                 v = qsh[g][1];
            meta[(size_t)(b0 + g) * 132 + tid] = v;
        }
    }
}

// ---------------- Kernel 2b: residual GEMM + interp + recon/L1 losses ----------------
__global__ __launch_bounds__(256) void resid_loss_kernel(
    const float* __restrict__ A, const unsigned short* __restrict__ rh,
    const float* __restrict__ res_b2, const unsigned short* __restrict__ pk,
    const float* __restrict__ meta, float* __restrict__ accums)
{
    __shared__ float ml[16 * 132];
    __shared__ float wred[4], wred2[4];

    const int tid  = threadIdx.x;
    const int w    = tid >> 6;
    const int lane = tid & 63;
    const int l15  = lane & 15;
    const int q    = lane >> 4;
    const int q8   = q << 3;
    const int q4   = q << 2;
    const int bg   = blockIdx.x >> 2;
    const int cc   = blockIdx.x & 3;
    const int b0   = bg << 4;

    for (int i = tid; i < 16 * 132; i += 256)
        ml[i] = meta[(size_t)b0 * 132 + i];
    __syncthreads();

    f32x4 acc[8];
    #pragma unroll
    for (int nt = 0; nt < 8; ++nt) acc[nt] = (f32x4){0.f,0.f,0.f,0.f};
    #pragma unroll
    for (int kk = 0; kk < 8; ++kk){
        bf16x8 af = *(const bf16x8*)(rh + ((size_t)(b0 + l15) << 8) + (kk << 5) + q8);
        #pragma unroll
        for (int nt = 0; nt < 8; ++nt){
            int ntg = (cc << 5) + (w << 3) + nt;
            bf16x8 bfr = *(const bf16x8*)(pk + O_RES2 + (size_t)((kk << 7) + ntg) * 512 + (lane << 3));
            acc[nt] = __builtin_amdgcn_mfma_f32_16x16x32_bf16(af, bfr, acc[nt], 0, 0, 0);
        }
    }

    float lsq = 0.f, ll1 = 0.f;
    #pragma unroll
    for (int nt = 0; nt < 8; ++nt){
        int e = (cc << 9) + (w << 7) + (nt << 4) + l15;
        float rbv = res_b2[e];
        int t = e >> 5, d = e & 31;
        float tf = (float)t;
        #pragma unroll
        for (int r = 0; r < 4; ++r){
            int g = q4 + r;
            const float* mg = &ml[g * 132];
            float p1 = mg[128], p2 = mg[129], q0 = mg[130], q1 = mg[131];
            float res = acc[nt][r] + rbv;
            int cnt = (p1 <= tf) + (p2 <= tf) + (tf >= 63.0f);
            int idx = cnt < 2 ? cnt : 2;
            float left  = idx == 0 ? 0.0f : (idx == 1 ? p1 : p2);
            float right = idx == 0 ? p1   : (idx == 1 ? p2 : 63.0f);
            float wgt = (tf - left) / (right - left + 1e-8f);
            wgt = fminf(fmaxf(wgt, 0.f), 1.f);
            float vl = mg[idx * 32 + d];
            float vr = mg[idx * 32 + 32 + d];
            float coarse = vl + wgt * (vr - vl);
            float a = A[((size_t)(b0 + g) << 11) + e];
            float fine = coarse + res;
            float recon = q0 * coarse + q1 * fine;
            float dd = recon - a;
            lsq += dd * dd;
            ll1 += fabsf(res);
        }
    }
    #pragma unroll
    for (int off = 32; off > 0; off >>= 1){
        lsq += __shfl_down(lsq, off);
        ll1 += __shfl_down(ll1, off);
    }
    if (lane == 0){ wred[w] = lsq; wred2[w] = ll1; }
    __syncthreads();
    if (tid == 0){
        atomicAdd(&accums[0], wred[0] + wred[1] + wred[2] + wred[3]);
        atomicAdd(&accums[1], wred2[0] + wred2[1] + wred2[2] + wred2[3]);
    }
}

// ---------------- Kernel 3: finalize ----------------
__global__ void finalize_kernel(const float* __restrict__ accums, float* __restrict__ out){
    float rs = accums[0], l1s = accums[1], ents = accums[2];
    float q0s = accums[3], q1s = accums[4], sps = accums[5];
    const float invN = 1.0f / (4096.0f * 2048.0f);
    const float invB = 1.0f / 4096.0f;
    float recon_loss = rs * invN;
    float l1   = l1s * invN;
    float ent  = -ents * invB;
    float mq0  = q0s * invB - 0.5f, mq1 = q1s * invB - 0.5f;
    float balance = mq0*mq0 + mq1*mq1;
    float spacing = sps * invB;
    out[0] = recon_loss + 0.05f*l1 + 0.01f*ent + 0.1f*balance + 0.1f*spacing;
}

extern "C" void kernel_launch(void* const* d_in, const int* in_sizes, int n_in,
                              void* d_out, int out_size, void* d_ws, size_t ws_size,
                              hipStream_t stream)
{
    const float* A      = (const float*)d_in[0];
    const float* W0     = (const float*)d_in[1];
    const float* B0     = (const float*)d_in[2];
    const float* W1     = (const float*)d_in[3];
    const float* B1     = (const float*)d_in[4];
    const float* W2     = (const float*)d_in[5];
    const float* B2     = (const float*)d_in[6];
    const float* proj_w = (const float*)d_in[7];
    const float* proj_b = (const float*)d_in[8];
    const float* val_w1 = (const float*)d_in[9];
    const float* val_b1 = (const float*)d_in[10];
    const float* val_w2 = (const float*)d_in[11];
    const float* val_b2 = (const float*)d_in[12];
    const float* pos_w1 = (const float*)d_in[13];
    const float* pos_b1 = (const float*)d_in[14];
    const float* pos_w2 = (const float*)d_in[15];
    const float* pos_b2 = (const float*)d_in[16];
    const float* res_w1 = (const float*)d_in[17];
    const float* res_b1 = (const float*)d_in[18];
    const float* res_w2 = (const float*)d_in[19];
    const float* res_b2 = (const float*)d_in[20];
    const float* mix_w  = (const float*)d_in[21];
    const float* mix_b  = (const float*)d_in[22];

    char* wsb = (char*)d_ws;
    float* accums = (float*)wsb;
    unsigned short* pooled = (unsigned short*)(wsb + 256);
    unsigned short* pkbuf  = (unsigned short*)(wsb + 256 + 2097152);
    unsigned short* rhbuf  = (unsigned short*)(wsb + 256 + 2097152 + (size_t)PK_TOTAL * 2);
    float* metabuf = (float*)(wsb + 256 + 2097152 + (size_t)PK_TOTAL * 2 + 2097152);

    hipMemsetAsync(accums, 0, 64 * sizeof(float), stream);

    hipLaunchKernelGGL(pack_weights, dim3((PK_TOTAL + 255) / 256), dim3(256), 0, stream,
                       W0, W1, W2, proj_w, val_w1, pos_w1, res_w1,
                       val_w2, res_w2, pos_w2, mix_w, pkbuf);

    hipLaunchKernelGGL(conv_mfma_kernel, dim3(NB), dim3(256), 0, stream,
                       A, B0, B1, B2,
                       pkbuf + O_WP0, pkbuf + O_WP1, pkbuf + O_WP2, pooled);

    hipLaunchKernelGGL(heads_a_kernel, dim3(NB / 16), dim3(256), 0, stream,
                       pooled, proj_b, val_b1, pos_b1, res_b1, val_b2, pos_b2, mix_b,
                       pkbuf, rhbuf, metabuf, accums);

    hipLaunchKernelGGL(resid_loss_kernel, dim3(NB / 16 * 4), dim3(256), 0, stream,
                       A, rhbuf, res_b2, pkbuf, metabuf, accums);

    hipLaunchKernelGGL(finalize_kernel, dim3(1), dim3(1), 0, stream,
                       accums, (float*)d_out);
}

// Round 3
// 568.827 us; speedup vs baseline: 1.1015x; 1.1015x over previous
//
#include <hip/hip_runtime.h>

#define NB 4096

typedef __attribute__((ext_vector_type(8)))  __bf16 bf16x8;
typedef __attribute__((ext_vector_type(4)))  float  f32x4;
typedef __attribute__((ext_vector_type(16))) float  f32x16;

__device__ __forceinline__ float gelu_fast(float x){
    float x2 = x * x;
    float y  = x * (0.79788456f + 0.03567741f * x2);
    float e  = __expf(2.0f * y);
    float t  = 1.0f - 2.0f / (e + 1.0f);
    return 0.5f * x * (1.0f + t);
}
__device__ __forceinline__ unsigned short f2bf(float x){
    unsigned b = __float_as_uint(x);
    b += 0x7fffu + ((b >> 16) & 1u);
    return (unsigned short)(b >> 16);
}

// ---------------- pack offsets (elements) ----------------
#define O_WP0  0
#define O_WP1  40960
#define O_WP2  368640
#define O_PROJ 696320
#define O_VAL1 761856
#define O_POS1 827392
#define O_RES1 892928
#define O_VAL2 958464
#define O_RES2 991232
#define O_POS2 1515520
#define O_MIX  1519616
#define PK_TOTAL 1523712

__device__ __forceinline__ unsigned short pack_std_elem(const float* W, int N, int t){
    int j = t & 7, lane = (t >> 3) & 63, rest = t >> 9;
    int ntcnt = N >> 4;
    int nt = rest % ntcnt, kk = rest / ntcnt;
    int n = nt*16 + (lane & 15), k = kk*32 + ((lane >> 4) << 3) + j;
    return f2bf(W[k * N + n]);
}
__device__ __forceinline__ unsigned short pack_pad_elem(const float* W, int Nreal, int t){
    int j = t & 7, lane = (t >> 3) & 63, kk = t >> 9;
    int n = lane & 15, k = kk*32 + ((lane >> 4) << 3) + j;
    return (n < Nreal) ? f2bf(W[k * Nreal + n]) : (unsigned short)0;
}

// conv sections packed for mfma_32x32x16: B[k][n], n = nt*32 + (lane&31),
// k_local = (lane>>5)*8 + j, K order = tap-major, 16-chan chunks inner.
__global__ __launch_bounds__(256) void pack_weights(
    const float* __restrict__ W0, const float* __restrict__ W1, const float* __restrict__ W2,
    const float* __restrict__ proj_w, const float* __restrict__ val_w1,
    const float* __restrict__ pos_w1, const float* __restrict__ res_w1,
    const float* __restrict__ val_w2, const float* __restrict__ res_w2,
    const float* __restrict__ pos_w2, const float* __restrict__ mix_w,
    unsigned short* __restrict__ pk)
{
    int idx = blockIdx.x * 256 + threadIdx.x;
    if (idx >= PK_TOTAL) return;
    if (idx < O_WP1){
        int t = idx;
        int j = t & 7, lane = (t >> 3) & 63, nt = (t >> 9) & 7, s = t >> 12;   // s 0..9
        int co = nt*32 + (lane & 31);
        int tap = s >> 1, ci = ((s & 1) << 4) + ((lane >> 5) << 3) + j;
        pk[idx] = f2bf(W0[co*160 + ci*5 + tap]);
    } else if (idx < O_WP2){
        int t = idx - O_WP1;
        int j = t & 7, lane = (t >> 3) & 63, nt = (t >> 9) & 7, s = t >> 12;   // s 0..79
        int co = nt*32 + (lane & 31);
        int tap = s >> 4, ci = ((s & 15) << 4) + ((lane >> 5) << 3) + j;
        pk[idx] = f2bf(W1[co*1280 + ci*5 + tap]);
    } else if (idx < O_PROJ){
        int t = idx - O_WP2;
        int j = t & 7, lane = (t >> 3) & 63, nt = (t >> 9) & 7, s = t >> 12;   // s 0..79
        int co = nt*32 + (lane & 31);
        int tap = s >> 4, ci = ((s & 15) << 4) + ((lane >> 5) << 3) + j;
        pk[idx] = f2bf(W2[co*1280 + ci*5 + tap]);
    }
    else if (idx < O_VAL1) pk[idx] = pack_std_elem(proj_w, 256, idx - O_PROJ);
    else if (idx < O_POS1) pk[idx] = pack_std_elem(val_w1, 256, idx - O_VAL1);
    else if (idx < O_RES1) pk[idx] = pack_std_elem(pos_w1, 256, idx - O_POS1);
    else if (idx < O_VAL2) pk[idx] = pack_std_elem(res_w1, 256, idx - O_RES1);
    else if (idx < O_RES2) pk[idx] = pack_std_elem(val_w2, 128, idx - O_VAL2);
    else if (idx < O_POS2) pk[idx] = pack_std_elem(res_w2, 2048, idx - O_RES2);
    else if (idx < O_MIX)  pk[idx] = pack_pad_elem(pos_w2, 4, idx - O_POS2);
    else                   pk[idx] = pack_pad_elem(mix_w, 2, idx - O_MIX);
}

// ---------------- Kernel 1: 32x32x16 MFMA conv, 2 batches/block, 2 blocks/CU ----------------
// LDS: 2*ht (2*35904) + xt (5440) = 77248 B -> 2 blocks/CU (8 waves, 2/SIMD)
// Weight (B) L2 traffic amortized over 2 batches: ~32 B/cyc/CU vs ~56 ceiling.
#define HT_S 264
#define XT_S 40

__global__ __launch_bounds__(256, 2) void conv_mfma_kernel(
    const float* __restrict__ A,
    const float* __restrict__ B0, const float* __restrict__ B1, const float* __restrict__ B2,
    const unsigned short* __restrict__ wp0, const unsigned short* __restrict__ wp1,
    const unsigned short* __restrict__ wp2,
    unsigned short* __restrict__ pooled)
{
    __shared__ __align__(16) unsigned short xt[68 * XT_S];
    __shared__ __align__(16) unsigned short ht[2][68 * HT_S];

    const int tid  = threadIdx.x;
    const int b0   = blockIdx.x * 2;
    const int w    = tid >> 6;
    const int lane = tid & 63;
    const int l31  = lane & 31;
    const int hi   = lane >> 5;
    const int hi8  = hi << 3;
    const int w2   = w << 1;

    for (int i = tid; i < 4 * HT_S; i += 256){
        int r = i / HT_S, c = i - r * HT_S;
        int rr = (r < 2 ? r : r + 64);
        ht[0][rr * HT_S + c] = 0;
        ht[1][rr * HT_S + c] = 0;
    }
    if (tid < 128){
        int r = tid >> 5, c = tid & 31;
        int rr = (r < 2 ? r : r + 64);
        xt[rr * XT_S + c] = 0;
    }

#define PACKX(BB) \
    { const float* Ab = A + (size_t)(b0 + (BB)) * 2048; \
      int e0 = tid << 3; \
      int t = e0 >> 5, c = e0 & 31; \
      const float4* p = (const float4*)(Ab + e0); \
      float4 v0 = p[0], v1 = p[1]; \
      union { unsigned short u[8]; bf16x8 v; } pkv; \
      pkv.u[0]=f2bf(v0.x); pkv.u[1]=f2bf(v0.y); pkv.u[2]=f2bf(v0.z); pkv.u[3]=f2bf(v0.w); \
      pkv.u[4]=f2bf(v1.x); pkv.u[5]=f2bf(v1.y); pkv.u[6]=f2bf(v1.z); pkv.u[7]=f2bf(v1.w); \
      *(bf16x8*)&xt[(t + 2) * XT_S + c] = pkv.v; }

    f32x16 acc[2][2][2];   // [batch][mt][nt]

#define ZEROALL \
    { _Pragma("unroll") for (int bb = 0; bb < 2; ++bb) \
      _Pragma("unroll") for (int mt = 0; mt < 2; ++mt) \
      _Pragma("unroll") for (int nt = 0; nt < 2; ++nt) \
      _Pragma("unroll") for (int r = 0; r < 16; ++r) acc[bb][mt][nt][r] = 0.f; }
// A fragment (ht): row = mt*32 + (lane&31) + tap, chans = chunk*16 + (lane>>5)*8 .. +8
#define LOADA_H32(BUF, HB, S) \
    { _Pragma("unroll") for (int mt = 0; mt < 2; ++mt) \
          BUF[mt] = *(const bf16x8*)&ht[HB][((mt << 5) + l31 + ((S) >> 4)) * HT_S + (((S) & 15) << 4) + hi8]; }
#define LOADA_X32(BUF, S) \
    { _Pragma("unroll") for (int mt = 0; mt < 2; ++mt) \
          BUF[mt] = *(const bf16x8*)&xt[((mt << 5) + l31 + ((S) >> 1)) * XT_S + (((S) & 1) << 4) + hi8]; }
#define LOADB32(BUF, S, WP) \
    { _Pragma("unroll") for (int nt = 0; nt < 2; ++nt) \
          BUF[nt] = *(const bf16x8*)((WP) + ((size_t)((((S) << 3) + w2 + nt) << 6) + lane) * 8); }
#define MF1(BB, A_, B_) \
    { _Pragma("unroll") for (int mt = 0; mt < 2; ++mt) \
      _Pragma("unroll") for (int nt = 0; nt < 2; ++nt) \
          acc[BB][mt][nt] = __builtin_amdgcn_mfma_f32_32x32x16_bf16(A_[mt], B_[nt], acc[BB][mt][nt], 0, 0, 0); }
#define MF2(A0_, A1_, B_) \
    { _Pragma("unroll") for (int mt = 0; mt < 2; ++mt) \
      _Pragma("unroll") for (int nt = 0; nt < 2; ++nt){ \
          acc[0][mt][nt] = __builtin_amdgcn_mfma_f32_32x32x16_bf16(A0_[mt], B_[nt], acc[0][mt][nt], 0, 0, 0); \
          acc[1][mt][nt] = __builtin_amdgcn_mfma_f32_32x32x16_bf16(A1_[mt], B_[nt], acc[1][mt][nt], 0, 0, 0); } }
// C/D: col = lane&31, row = (r&3) + 8*(r>>2) + 4*(lane>>5)  [m74/m101]
#define EPI32(BB, BIAS) \
    { float bvn[2]; \
      _Pragma("unroll") for (int nt = 0; nt < 2; ++nt) bvn[nt] = (BIAS)[((w2 + nt) << 5) + l31]; \
      _Pragma("unroll") for (int mt = 0; mt < 2; ++mt) \
      _Pragma("unroll") for (int nt = 0; nt < 2; ++nt) \
      _Pragma("unroll") for (int r = 0; r < 16; ++r){ \
          int row = (mt << 5) + (r & 3) + ((r >> 2) << 3) + (hi << 2) + 2; \
          float v = gelu_fast(acc[BB][mt][nt][r] + bvn[nt]); \
          ht[BB][row * HT_S + ((w2 + nt) << 5) + l31] = f2bf(v); } }

// conv0: 10 K-steps, depth-2, single batch per pass
#define CONV0(BB) \
    { bf16x8 Ba[2], Bb[2], Xa[2], Xb[2]; \
      LOADB32(Ba, 0, wp0); LOADA_X32(Xa, 0); \
      LOADB32(Bb, 1, wp0); LOADA_X32(Xb, 1); \
      for (int s = 0; s < 8; s += 2){ \
          MF1(BB, Xa, Ba); LOADB32(Ba, s + 2, wp0); LOADA_X32(Xa, s + 2); \
          MF1(BB, Xb, Bb); LOADB32(Bb, s + 3, wp0); LOADA_X32(Xb, s + 3); \
      } \
      MF1(BB, Xa, Ba); \
      MF1(BB, Xb, Bb); }

// conv1/conv2: 80 K-steps, both batches share each B fragment, depth-2 pipeline
#define CONV_L2B(WP) \
    { bf16x8 Ba[2], Bb[2], A0a[2], A0b[2], A1a[2], A1b[2]; \
      LOADB32(Ba, 0, WP); LOADA_H32(A0a, 0, 0); LOADA_H32(A1a, 1, 0); \
      LOADB32(Bb, 1, WP); LOADA_H32(A0b, 0, 1); LOADA_H32(A1b, 1, 1); \
      for (int s = 0; s < 78; s += 2){ \
          MF2(A0a, A1a, Ba); LOADB32(Ba, s + 2, WP); LOADA_H32(A0a, 0, s + 2); LOADA_H32(A1a, 1, s + 2); \
          MF2(A0b, A1b, Bb); LOADB32(Bb, s + 3, WP); LOADA_H32(A0b, 0, s + 3); LOADA_H32(A1b, 1, s + 3); \
      } \
      MF2(A0a, A1a, Ba); \
      MF2(A0b, A1b, Bb); }

    // ---- conv0: two passes sharing the single xt buffer ----
    PACKX(0);
    __syncthreads();
    ZEROALL;
    CONV0(0);
    __syncthreads();          // all xt reads done
    PACKX(1);
    __syncthreads();
    CONV0(1);
    EPI32(0, B0);
    EPI32(1, B0);
    __syncthreads();

    // ---- conv1 ----
    ZEROALL;
    CONV_L2B(wp1);
    __syncthreads();
    EPI32(0, B1);
    EPI32(1, B1);
    __syncthreads();

    // ---- conv2 + mean pool ----
    ZEROALL;
    CONV_L2B(wp2);
    {
        float bvn[2];
        #pragma unroll
        for (int nt = 0; nt < 2; ++nt) bvn[nt] = B2[((w2 + nt) << 5) + l31];
        #pragma unroll
        for (int bb = 0; bb < 2; ++bb){
            float s0[2];
            #pragma unroll
            for (int nt = 0; nt < 2; ++nt){
                float a = 0.f;
                #pragma unroll
                for (int mt = 0; mt < 2; ++mt)
                    #pragma unroll
                    for (int r = 0; r < 16; ++r)
                        a += gelu_fast(acc[bb][mt][nt][r] + bvn[nt]);
                s0[nt] = a;
            }
            #pragma unroll
            for (int nt = 0; nt < 2; ++nt) s0[nt] += __shfl_xor(s0[nt], 32);
            if (hi == 0){
                #pragma unroll
                for (int nt = 0; nt < 2; ++nt)
                    pooled[(size_t)(b0 + bb) * 256 + ((w2 + nt) << 5) + l31] = f2bf(s0[nt] * (1.0f / 64.0f));
            }
        }
    }
}

// ---------------- Kernel 2a: heads stages A-C, 16 batches/block ----------------
#define AS 264

__global__ __launch_bounds__(256) void heads_a_kernel(
    const unsigned short* __restrict__ pooled,
    const float* __restrict__ proj_b, const float* __restrict__ val_b1,
    const float* __restrict__ pos_b1, const float* __restrict__ res_b1,
    const float* __restrict__ val_b2, const float* __restrict__ pos_b2,
    const float* __restrict__ mix_b,
    const unsigned short* __restrict__ pk,
    unsigned short* __restrict__ rh, float* __restrict__ meta,
    float* __restrict__ accums)
{
    __shared__ unsigned short pb [16 * AS];
    __shared__ unsigned short eb [16 * AS];
    __shared__ unsigned short vb [16 * AS];
    __shared__ unsigned short phb[16 * AS];
    __shared__ unsigned short rhb[16 * AS];
    __shared__ float av [16 * 132];
    __shared__ float avs[16 * 132];
    __shared__ float psort[16][4];
    __shared__ int   rank [16][4];
    __shared__ float qsh  [16][2];
    __shared__ float mlsh [16][2];
    __shared__ float sposh[16][4];

    const int tid  = threadIdx.x;
    const int b0   = blockIdx.x * 16;
    const int w    = tid >> 6;
    const int lane = tid & 63;
    const int l15  = lane & 15;
    const int q    = lane >> 4;
    const int q8   = q << 3;
    const int q4   = q << 2;

    {
        int g = tid >> 4, seg = tid & 15;
        const unsigned short* ps = pooled + ((size_t)(b0 + g) << 8) + (seg << 4);
        bf16x8 a0 = *(const bf16x8*)ps;
        bf16x8 a1 = *(const bf16x8*)(ps + 8);
        *(bf16x8*)&pb[g * AS + (seg << 4)]     = a0;
        *(bf16x8*)&pb[g * AS + (seg << 4) + 8] = a1;
    }
    __syncthreads();

#define HGEMM256(ASRC, GOFF, BIAS, DST) \
    { f32x4 hacc[4]; \
      _Pragma("unroll") for (int nt = 0; nt < 4; ++nt) hacc[nt] = (f32x4){0.f,0.f,0.f,0.f}; \
      _Pragma("unroll") for (int kk = 0; kk < 8; ++kk){ \
          bf16x8 af = *(const bf16x8*)&(ASRC)[l15 * AS + (kk << 5) + q8]; \
          _Pragma("unroll") for (int nt = 0; nt < 4; ++nt){ \
              bf16x8 bfr = *(const bf16x8*)(pk + (GOFF) + (size_t)((((kk << 4) + (w << 2) + nt) << 6) + lane) * 8); \
              hacc[nt] = __builtin_amdgcn_mfma_f32_16x16x32_bf16(af, bfr, hacc[nt], 0, 0, 0); } } \
      _Pragma("unroll") for (int nt = 0; nt < 4; ++nt){ \
          int n = (w << 6) + (nt << 4) + l15; \
          float bv = (BIAS)[n]; \
          _Pragma("unroll") for (int r = 0; r < 4; ++r) \
              (DST)[(q4 + r) * AS + n] = f2bf(gelu_fast(hacc[nt][r] + bv)); } }

    HGEMM256(pb, O_PROJ, proj_b, eb);
    __syncthreads();

    HGEMM256(eb, O_VAL1, val_b1, vb);
    HGEMM256(eb, O_POS1, pos_b1, phb);
    HGEMM256(eb, O_RES1, res_b1, rhb);
    __syncthreads();

    {
        f32x4 acc2[2];
        #pragma unroll
        for (int nt = 0; nt < 2; ++nt) acc2[nt] = (f32x4){0.f,0.f,0.f,0.f};
        #pragma unroll
        for (int kk = 0; kk < 8; ++kk){
            bf16x8 af = *(const bf16x8*)&vb[l15 * AS + (kk << 5) + q8];
            #pragma unroll
            for (int nt = 0; nt < 2; ++nt){
                bf16x8 bfr = *(const bf16x8*)(pk + O_VAL2 + (size_t)(((kk*8 + w*2 + nt) << 6) + lane) * 8);
                acc2[nt] = __builtin_amdgcn_mfma_f32_16x16x32_bf16(af, bfr, acc2[nt], 0, 0, 0);
            }
        }
        #pragma unroll
        for (int nt = 0; nt < 2; ++nt){
            int j = (w << 5) + (nt << 4) + l15;
            float bv = val_b2[j];
            #pragma unroll
            for (int r = 0; r < 4; ++r)
                av[(q4 + r) * 132 + j] = acc2[nt][r] + bv;
        }
    }
    if (w == 0){
        f32x4 accp = (f32x4){0.f,0.f,0.f,0.f};
        #pragma unroll
        for (int kk = 0; kk < 8; ++kk){
            bf16x8 af  = *(const bf16x8*)&phb[l15 * AS + (kk << 5) + q8];
            bf16x8 bfr = *(const bf16x8*)(pk + O_POS2 + (size_t)((kk << 6) + lane) * 8);
            accp = __builtin_amdgcn_mfma_f32_16x16x32_bf16(af, bfr, accp, 0, 0, 0);
        }
        if (l15 < 4){
            float bv = pos_b2[l15];
            #pragma unroll
            for (int r = 0; r < 4; ++r){
                float raw = accp[r] + bv;
                sposh[q4 + r][l15] = 63.0f / (1.0f + __expf(-raw));
            }
        }
    } else if (w == 1){
        f32x4 accm = (f32x4){0.f,0.f,0.f,0.f};
        #pragma unroll
        for (int kk = 0; kk < 8; ++kk){
            bf16x8 af  = *(const bf16x8*)&eb[l15 * AS + (kk << 5) + q8];
            bf16x8 bfr = *(const bf16x8*)(pk + O_MIX + (size_t)((kk << 6) + lane) * 8);
            accm = __builtin_amdgcn_mfma_f32_16x16x32_bf16(af, bfr, accm, 0, 0, 0);
        }
        if (l15 < 2){
            #pragma unroll
            for (int r = 0; r < 4; ++r)
                mlsh[q4 + r][l15] = accm[r] + mix_b[l15];
        }
    }
    __syncthreads();

    if (tid < 16){
        int g = tid;
        float sv[4] = { sposh[g][0], sposh[g][1], sposh[g][2], sposh[g][3] };
        #pragma unroll
        for (int i = 0; i < 4; ++i){
            int r = 0;
            #pragma unroll
            for (int jj = 0; jj < 4; ++jj){
                r += (sv[jj] < sv[i]) ? 1 : 0;
                if (jj < i) r += (sv[jj] == sv[i]) ? 1 : 0;
            }
            rank[g][i] = r;
            psort[g][r] = sv[i];
        }
        psort[g][0] = 0.0f; psort[g][3] = 63.0f;
        float p1 = psort[g][1], p2 = psort[g][2];
        float g1 = p1, g2 = p2 - p1, g3 = 63.0f - p2;
        const float MG = 10.5f;
        float r1 = fmaxf(MG - g1, 0.f), r2 = fmaxf(MG - g2, 0.f), r3 = fmaxf(MG - g3, 0.f);
        float sp = (r1*r1 + r2*r2 + r3*r3) * (1.0f / 3.0f);
        float l0 = mlsh[g][0], l1 = mlsh[g][1];
        float m = fmaxf(l0, l1);
        float e0 = __expf(l0 - m), e1 = __expf(l1 - m);
        float inv = 1.0f / (e0 + e1);
        float q0 = e0 * inv, q1 = e1 * inv;
        qsh[g][0] = q0; qsh[g][1] = q1;
        float entc = q0 * logf(q0 + 1e-8f) + q1 * logf(q1 + 1e-8f);
        atomicAdd(&accums[2], entc);
        atomicAdd(&accums[3], q0);
        atomicAdd(&accums[4], q1);
        atomicAdd(&accums[5], sp);
    }
    __syncthreads();

    #pragma unroll
    for (int u2 = 0; u2 < 8; ++u2){
        int idx2 = tid * 8 + u2;
        int g = idx2 >> 7, j = idx2 & 127;
        avs[g * 132 + rank[g][j >> 5] * 32 + (j & 31)] = av[g * 132 + j];
    }
    __syncthreads();

    {
        int g = tid >> 4, c16 = (tid & 15) << 4;
        bf16x8 a0 = *(const bf16x8*)&rhb[g * AS + c16];
        bf16x8 a1 = *(const bf16x8*)&rhb[g * AS + c16 + 8];
        unsigned short* dst = rh + ((size_t)(b0 + g) << 8) + c16;
        *(bf16x8*)dst       = a0;
        *(bf16x8*)(dst + 8) = a1;
    }
    if (tid < 132){
        for (int g = 0; g < 16; ++g){
            float v;
            if (tid < 128)       v = avs[g * 132 + tid];
            else if (tid == 128) v = psort[g][1];
            else if (tid == 129) v = psort[g][2];
            else if (tid == 130) v = qsh[g][0];
            else                 v = qsh[g][1];
            meta[(size_t)(b0 + g) * 132 + tid] = v;
        }
    }
}

// ---------------- Kernel 2b: residual GEMM + interp + recon/L1 losses ----------------
__global__ __launch_bounds__(256) void resid_loss_kernel(
    const float* __restrict__ A, const unsigned short* __restrict__ rh,
    const float* __restrict__ res_b2, const unsigned short* __restrict__ pk,
    const float* __restrict__ meta, float* __restrict__ accums)
{
    __shared__ float ml[16 * 132];
    __shared__ float wred[4], wred2[4];

    const int tid  = threadIdx.x;
    const int w    = tid >> 6;
    const int lane = tid & 63;
    const int l15  = lane & 15;
    const int q    = lane >> 4;
    const int q8   = q << 3;
    const int q4   = q << 2;
    const int bg   = blockIdx.x >> 2;
    const int cc   = blockIdx.x & 3;
    const int b0   = bg << 4;

    for (int i = tid; i < 16 * 132; i += 256)
        ml[i] = meta[(size_t)b0 * 132 + i];
    __syncthreads();

    f32x4 acc[8];
    #pragma unroll
    for (int nt = 0; nt < 8; ++nt) acc[nt] = (f32x4){0.f,0.f,0.f,0.f};
    #pragma unroll
    for (int kk = 0; kk < 8; ++kk){
        bf16x8 af = *(const bf16x8*)(rh + ((size_t)(b0 + l15) << 8) + (kk << 5) + q8);
        #pragma unroll
        for (int nt = 0; nt < 8; ++nt){
            int ntg = (cc << 5) + (w << 3) + nt;
            bf16x8 bfr = *(const bf16x8*)(pk + O_RES2 + (size_t)((kk << 7) + ntg) * 512 + (lane << 3));
            acc[nt] = __builtin_amdgcn_mfma_f32_16x16x32_bf16(af, bfr, acc[nt], 0, 0, 0);
        }
    }

    float lsq = 0.f, ll1 = 0.f;
    #pragma unroll
    for (int nt = 0; nt < 8; ++nt){
        int e = (cc << 9) + (w << 7) + (nt << 4) + l15;
        float rbv = res_b2[e];
        int t = e >> 5, d = e & 31;
        float tf = (float)t;
        #pragma unroll
        for (int r = 0; r < 4; ++r){
            int g = q4 + r;
            const float* mg = &ml[g * 132];
            float p1 = mg[128], p2 = mg[129], q0 = mg[130], q1 = mg[131];
            float res = acc[nt][r] + rbv;
            int cnt = (p1 <= tf) + (p2 <= tf) + (tf >= 63.0f);
            int idx = cnt < 2 ? cnt : 2;
            float left  = idx == 0 ? 0.0f : (idx == 1 ? p1 : p2);
            float right = idx == 0 ? p1   : (idx == 1 ? p2 : 63.0f);
            float wgt = (tf - left) / (right - left + 1e-8f);
            wgt = fminf(fmaxf(wgt, 0.f), 1.f);
            float vl = mg[idx * 32 + d];
            float vr = mg[idx * 32 + 32 + d];
            float coarse = vl + wgt * (vr - vl);
            float a = A[((size_t)(b0 + g) << 11) + e];
            float fine = coarse + res;
            float recon = q0 * coarse + q1 * fine;
            float dd = recon - a;
            lsq += dd * dd;
            ll1 += fabsf(res);
        }
    }
    #pragma unroll
    for (int off = 32; off > 0; off >>= 1){
        lsq += __shfl_down(lsq, off);
        ll1 += __shfl_down(ll1, off);
    }
    if (lane == 0){ wred[w] = lsq; wred2[w] = ll1; }
    __syncthreads();
    if (tid == 0){
        atomicAdd(&accums[0], wred[0] + wred[1] + wred[2] + wred[3]);
        atomicAdd(&accums[1], wred2[0] + wred2[1] + wred2[2] + wred2[3]);
    }
}

// ---------------- Kernel 3: finalize ----------------
__global__ void finalize_kernel(const float* __restrict__ accums, float* __restrict__ out){
    float rs = accums[0], l1s = accums[1], ents = accums[2];
    float q0s = accums[3], q1s = accums[4], sps = accums[5];
    const float invN = 1.0f / (4096.0f * 2048.0f);
    const float invB = 1.0f / 4096.0f;
    float recon_loss = rs * invN;
    float l1   = l1s * invN;
    float ent  = -ents * invB;
    float mq0  = q0s * invB - 0.5f, mq1 = q1s * invB - 0.5f;
    float balance = mq0*mq0 + mq1*mq1;
    float spacing = sps * invB;
    out[0] = recon_loss + 0.05f*l1 + 0.01f*ent + 0.1f*balance + 0.1f*spacing;
}

extern "C" void kernel_launch(void* const* d_in, const int* in_sizes, int n_in,
                              void* d_out, int out_size, void* d_ws, size_t ws_size,
                              hipStream_t stream)
{
    const float* A      = (const float*)d_in[0];
    const float* W0     = (const float*)d_in[1];
    const float* B0     = (const float*)d_in[2];
    const float* W1     = (const float*)d_in[3];
    const float* B1     = (const float*)d_in[4];
    const float* W2     = (const float*)d_in[5];
    const float* B2     = (const float*)d_in[6];
    const float* proj_w = (const float*)d_in[7];
    const float* proj_b = (const float*)d_in[8];
    const float* val_w1 = (const float*)d_in[9];
    const float* val_b1 = (const float*)d_in[10];
    const float* val_w2 = (const float*)d_in[11];
    const float* val_b2 = (const float*)d_in[12];
    const float* pos_w1 = (const float*)d_in[13];
    const float* pos_b1 = (const float*)d_in[14];
    const float* pos_w2 = (const float*)d_in[15];
    const float* pos_b2 = (const float*)d_in[16];
    const float* res_w1 = (const float*)d_in[17];
    const float* res_b1 = (const float*)d_in[18];
    const float* res_w2 = (const float*)d_in[19];
    const float* res_b2 = (const float*)d_in[20];
    const float* mix_w  = (const float*)d_in[21];
    const float* mix_b  = (const float*)d_in[22];

    char* wsb = (char*)d_ws;
    float* accums = (float*)wsb;
    unsigned short* pooled = (unsigned short*)(wsb + 256);
    unsigned short* pkbuf  = (unsigned short*)(wsb + 256 + 2097152);
    unsigned short* rhbuf  = (unsigned short*)(wsb + 256 + 2097152 + (size_t)PK_TOTAL * 2);
    float* metabuf = (float*)(wsb + 256 + 2097152 + (size_t)PK_TOTAL * 2 + 2097152);

    hipMemsetAsync(accums, 0, 64 * sizeof(float), stream);

    hipLaunchKernelGGL(pack_weights, dim3((PK_TOTAL + 255) / 256), dim3(256), 0, stream,
                       W0, W1, W2, proj_w, val_w1, pos_w1, res_w1,
                       val_w2, res_w2, pos_w2, mix_w, pkbuf);

    hipLaunchKernelGGL(conv_mfma_kernel, dim3(NB / 2), dim3(256), 0, stream,
                       A, B0, B1, B2,
                       pkbuf + O_WP0, pkbuf + O_WP1, pkbuf + O_WP2, pooled);

    hipLaunchKernelGGL(heads_a_kernel, dim3(NB / 16), dim3(256), 0, stream,
                       pooled, proj_b, val_b1, pos_b1, res_b1, val_b2, pos_b2, mix_b,
                       pkbuf, rhbuf, metabuf, accums);

    hipLaunchKernelGGL(resid_loss_kernel, dim3(NB / 16 * 4), dim3(256), 0, stream,
                       A, rhbuf, res_b2, pkbuf, metabuf, accums);

    hipLaunchKernelGGL(finalize_kernel, dim3(1), dim3(1), 0, stream,
                       accums, (float*)d_out);
}

// Round 4
// 528.960 us; speedup vs baseline: 1.1845x; 1.0754x over previous
//
#include <hip/hip_runtime.h>

#define NB 4096

typedef __attribute__((ext_vector_type(8)))  __bf16 bf16x8;
typedef __attribute__((ext_vector_type(4)))  float  f32x4;
typedef __attribute__((ext_vector_type(16))) float  f32x16;
typedef long fp8x8;   // 8 x e4m3 bytes in 2 VGPRs

__device__ __forceinline__ float gelu_fast(float x){
    float x2 = x * x;
    float y  = x * (0.79788456f + 0.03567741f * x2);
    float e  = __expf(2.0f * y);
    float t  = 1.0f - 2.0f / (e + 1.0f);
    return 0.5f * x * (1.0f + t);
}
__device__ __forceinline__ unsigned short f2bf(float x){
    unsigned b = __float_as_uint(x);
    b += 0x7fffu + ((b >> 16) & 1u);
    return (unsigned short)(b >> 16);
}
__device__ __forceinline__ unsigned char f2fp8(float x){
    int p = __builtin_amdgcn_cvt_pk_fp8_f32(x, x, 0, false);
    return (unsigned char)(p & 0xff);
}

// ---------------- pack offsets (elements) ----------------
#define O_WP0  0
#define O_WP1  40960
#define O_WP2  368640
#define O_PROJ 696320
#define O_VAL1 761856
#define O_POS1 827392
#define O_RES1 892928
#define O_VAL2 958464
#define O_RES2 991232
#define O_POS2 1515520
#define O_MIX  1519616
#define PK_TOTAL 1523712

#define WQ_BYTES 327680   // 256*1280 fp8 bytes per conv layer

__device__ __forceinline__ unsigned short pack_std_elem(const float* W, int N, int t){
    int j = t & 7, lane = (t >> 3) & 63, rest = t >> 9;
    int ntcnt = N >> 4;
    int nt = rest % ntcnt, kk = rest / ntcnt;
    int n = nt*16 + (lane & 15), k = kk*32 + ((lane >> 4) << 3) + j;
    return f2bf(W[k * N + n]);
}
__device__ __forceinline__ unsigned short pack_pad_elem(const float* W, int Nreal, int t){
    int j = t & 7, lane = (t >> 3) & 63, kk = t >> 9;
    int n = lane & 15, k = kk*32 + ((lane >> 4) << 3) + j;
    return (n < Nreal) ? f2bf(W[k * Nreal + n]) : (unsigned short)0;
}
// fp8 conv pack: byte idx t -> j=t&7, lane=(t>>3)&63, ntg=(t>>9)&7, S=t>>12 (0..79)
// n = ntg*32+(lane&31); tap=S>>4; ci=(S&15)*16+(lane>>5)*8+j; value = W[n][ci][tap]*32
__device__ __forceinline__ unsigned char pack_fp8_elem(const float* W, int t){
    int j = t & 7, lane = (t >> 3) & 63, ntg = (t >> 9) & 7, S = t >> 12;
    int n = ntg*32 + (lane & 31);
    int tap = S >> 4, ci = ((S & 15) << 4) + ((lane >> 5) << 3) + j;
    return f2fp8(W[n*1280 + ci*5 + tap] * 32.0f);
}

__global__ __launch_bounds__(256) void pack_weights(
    const float* __restrict__ W0, const float* __restrict__ W1, const float* __restrict__ W2,
    const float* __restrict__ proj_w, const float* __restrict__ val_w1,
    const float* __restrict__ pos_w1, const float* __restrict__ res_w1,
    const float* __restrict__ val_w2, const float* __restrict__ res_w2,
    const float* __restrict__ pos_w2, const float* __restrict__ mix_w,
    unsigned short* __restrict__ pk,
    unsigned char* __restrict__ wq1, unsigned char* __restrict__ wq2)
{
    int idx = blockIdx.x * 256 + threadIdx.x;
    if (idx >= PK_TOTAL) return;
    if (idx < O_WP1){
        int t = idx;
        int j = t & 7, lane = (t >> 3) & 63, nt = (t >> 9) & 7, s = t >> 12;   // s 0..9
        int co = nt*32 + (lane & 31);
        int tap = s >> 1, ci = ((s & 1) << 4) + ((lane >> 5) << 3) + j;
        pk[idx] = f2bf(W0[co*160 + ci*5 + tap]);
    } else if (idx < O_WP2){
        wq1[idx - O_WP1] = pack_fp8_elem(W1, idx - O_WP1);
    } else if (idx < O_PROJ){
        wq2[idx - O_WP2] = pack_fp8_elem(W2, idx - O_WP2);
    }
    else if (idx < O_VAL1) pk[idx] = pack_std_elem(proj_w, 256, idx - O_PROJ);
    else if (idx < O_POS1) pk[idx] = pack_std_elem(val_w1, 256, idx - O_VAL1);
    else if (idx < O_RES1) pk[idx] = pack_std_elem(pos_w1, 256, idx - O_POS1);
    else if (idx < O_VAL2) pk[idx] = pack_std_elem(res_w1, 256, idx - O_RES1);
    else if (idx < O_RES2) pk[idx] = pack_std_elem(val_w2, 128, idx - O_VAL2);
    else if (idx < O_POS2) pk[idx] = pack_std_elem(res_w2, 2048, idx - O_RES2);
    else if (idx < O_MIX)  pk[idx] = pack_pad_elem(pos_w2, 4, idx - O_POS2);
    else                   pk[idx] = pack_pad_elem(mix_w, 2, idx - O_MIX);
}

// ---------------- Kernel 1: fp8 32x32x16 MFMA conv, 2 batches/block, 3 blocks/CU ----------------
// LDS: 2 x ht8 (2*17952) + xt (5440) = 41344 B -> 3 blocks/CU.
// Activations stored as e4m3 * 8; conv1/2 weights e4m3 * 32; EPI rescales acc by 1/256.
#define HT8_S 264
#define XT_S 40
#define INV256 0.00390625f

__global__ __launch_bounds__(256, 3) void conv_mfma_kernel(
    const float* __restrict__ A,
    const float* __restrict__ B0, const float* __restrict__ B1, const float* __restrict__ B2,
    const unsigned short* __restrict__ wp0,
    const unsigned char* __restrict__ wq1, const unsigned char* __restrict__ wq2,
    unsigned short* __restrict__ pooled)
{
    __shared__ __align__(16) unsigned short xt[68 * XT_S];
    __shared__ __align__(16) unsigned char  ht8[2][68 * HT8_S];

    const int tid  = threadIdx.x;
    const int b0   = blockIdx.x * 2;
    const int w    = tid >> 6;
    const int lane = tid & 63;
    const int l31  = lane & 31;
    const int hi   = lane >> 5;
    const int hi8  = hi << 3;
    const int w2   = w << 1;

    for (int i = tid; i < 4 * HT8_S; i += 256){
        int r = i / HT8_S, c = i - r * HT8_S;
        int rr = (r < 2 ? r : r + 64);
        ht8[0][rr * HT8_S + c] = 0;
        ht8[1][rr * HT8_S + c] = 0;
    }
    if (tid < 128){
        int r = tid >> 5, c = tid & 31;
        int rr = (r < 2 ? r : r + 64);
        xt[rr * XT_S + c] = 0;
    }

#define PACKX(BB) \
    { const float* Ab = A + (size_t)(b0 + (BB)) * 2048; \
      int e0 = tid << 3; \
      int t = e0 >> 5, c = e0 & 31; \
      const float4* p = (const float4*)(Ab + e0); \
      float4 v0 = p[0], v1 = p[1]; \
      union { unsigned short u[8]; bf16x8 v; } pkv; \
      pkv.u[0]=f2bf(v0.x); pkv.u[1]=f2bf(v0.y); pkv.u[2]=f2bf(v0.z); pkv.u[3]=f2bf(v0.w); \
      pkv.u[4]=f2bf(v1.x); pkv.u[5]=f2bf(v1.y); pkv.u[6]=f2bf(v1.z); pkv.u[7]=f2bf(v1.w); \
      *(bf16x8*)&xt[(t + 2) * XT_S + c] = pkv.v; }

    f32x16 acc[2][2][2];   // [batch][mt][nt]

#define ZEROALL \
    { _Pragma("unroll") for (int bb = 0; bb < 2; ++bb) \
      _Pragma("unroll") for (int mt = 0; mt < 2; ++mt) \
      _Pragma("unroll") for (int nt = 0; nt < 2; ++nt) \
      _Pragma("unroll") for (int r = 0; r < 16; ++r) acc[bb][mt][nt][r] = 0.f; }

// bf16 conv0 pieces (xt + wp0), as verified in R3
#define LOADA_X32(BUF, S) \
    { _Pragma("unroll") for (int mt = 0; mt < 2; ++mt) \
          BUF[mt] = *(const bf16x8*)&xt[((mt << 5) + l31 + ((S) >> 1)) * XT_S + (((S) & 1) << 4) + hi8]; }
#define LOADB32(BUF, S, WP) \
    { _Pragma("unroll") for (int nt = 0; nt < 2; ++nt) \
          BUF[nt] = *(const bf16x8*)((WP) + ((size_t)((((S) << 3) + w2 + nt) << 6) + lane) * 8); }
#define MF1(BB, A_, B_) \
    { _Pragma("unroll") for (int mt = 0; mt < 2; ++mt) \
      _Pragma("unroll") for (int nt = 0; nt < 2; ++nt) \
          acc[BB][mt][nt] = __builtin_amdgcn_mfma_f32_32x32x16_bf16(A_[mt], B_[nt], acc[BB][mt][nt], 0, 0, 0); }

// fp8 pieces (ht8 + wq)
#define LOADA8(BUF, HB, S) \
    { _Pragma("unroll") for (int mt = 0; mt < 2; ++mt) \
          BUF[mt] = *(const fp8x8*)&ht8[HB][((mt << 5) + l31 + ((S) >> 4)) * HT8_S + (((S) & 15) << 4) + hi8]; }
#define LOADB8(BUF, S, WQ) \
    { _Pragma("unroll") for (int nt = 0; nt < 2; ++nt) \
          BUF[nt] = *(const fp8x8*)((WQ) + ((size_t)((((S) << 3) + w2 + nt) << 6) + lane) * 8); }
#define MF8_2(A0_, A1_, B_) \
    { _Pragma("unroll") for (int mt = 0; mt < 2; ++mt) \
      _Pragma("unroll") for (int nt = 0; nt < 2; ++nt){ \
          acc[0][mt][nt] = __builtin_amdgcn_mfma_f32_32x32x16_fp8_fp8(A0_[mt], B_[nt], acc[0][mt][nt], 0, 0, 0); \
          acc[1][mt][nt] = __builtin_amdgcn_mfma_f32_32x32x16_fp8_fp8(A1_[mt], B_[nt], acc[1][mt][nt], 0, 0, 0); } }

// C/D: col = lane&31, row = (r&3) + 8*(r>>2) + 4*(lane>>5)  [verified R2/R3]
// store fp8( gelu(acc*SC + bias) * 8 )
#define EPI8(BB, BIAS, SC) \
    { float bvn[2]; \
      _Pragma("unroll") for (int nt = 0; nt < 2; ++nt) bvn[nt] = (BIAS)[((w2 + nt) << 5) + l31]; \
      _Pragma("unroll") for (int mt = 0; mt < 2; ++mt) \
      _Pragma("unroll") for (int nt = 0; nt < 2; ++nt) \
      _Pragma("unroll") for (int r = 0; r < 16; ++r){ \
          int row = (mt << 5) + (r & 3) + ((r >> 2) << 3) + (hi << 2) + 2; \
          float v = gelu_fast(acc[BB][mt][nt][r] * (SC) + bvn[nt]); \
          ht8[BB][row * HT8_S + ((w2 + nt) << 5) + l31] = f2fp8(v * 8.0f); } }

// conv0: 10 K-steps bf16, depth-2, single batch per pass
#define CONV0(BB) \
    { bf16x8 Ba[2], Bb[2], Xa[2], Xb[2]; \
      LOADB32(Ba, 0, wp0); LOADA_X32(Xa, 0); \
      LOADB32(Bb, 1, wp0); LOADA_X32(Xb, 1); \
      for (int s = 0; s < 8; s += 2){ \
          MF1(BB, Xa, Ba); LOADB32(Ba, s + 2, wp0); LOADA_X32(Xa, s + 2); \
          MF1(BB, Xb, Bb); LOADB32(Bb, s + 3, wp0); LOADA_X32(Xb, s + 3); \
      } \
      MF1(BB, Xa, Ba); \
      MF1(BB, Xb, Bb); }

// conv1/conv2: 80 K-steps fp8, both batches share each B fragment, depth-2 pipeline
#define CONV_F8(WQ) \
    { fp8x8 Ba[2], Bb[2], A0a[2], A0b[2], A1a[2], A1b[2]; \
      LOADB8(Ba, 0, WQ); LOADA8(A0a, 0, 0); LOADA8(A1a, 1, 0); \
      LOADB8(Bb, 1, WQ); LOADA8(A0b, 0, 1); LOADA8(A1b, 1, 1); \
      for (int s = 0; s < 78; s += 2){ \
          MF8_2(A0a, A1a, Ba); LOADB8(Ba, s + 2, WQ); LOADA8(A0a, 0, s + 2); LOADA8(A1a, 1, s + 2); \
          MF8_2(A0b, A1b, Bb); LOADB8(Bb, s + 3, WQ); LOADA8(A0b, 0, s + 3); LOADA8(A1b, 1, s + 3); \
      } \
      MF8_2(A0a, A1a, Ba); \
      MF8_2(A0b, A1b, Bb); }

    // ---- conv0: two passes sharing the single xt buffer ----
    PACKX(0);
    __syncthreads();
    ZEROALL;
    CONV0(0);
    __syncthreads();          // all xt reads done
    PACKX(1);
    __syncthreads();
    CONV0(1);
    EPI8(0, B0, 1.0f);
    EPI8(1, B0, 1.0f);
    __syncthreads();

    // ---- conv1 (fp8) ----
    ZEROALL;
    CONV_F8(wq1);
    __syncthreads();
    EPI8(0, B1, INV256);
    EPI8(1, B1, INV256);
    __syncthreads();

    // ---- conv2 (fp8) + mean pool ----
    ZEROALL;
    CONV_F8(wq2);
    {
        float bvn[2];
        #pragma unroll
        for (int nt = 0; nt < 2; ++nt) bvn[nt] = B2[((w2 + nt) << 5) + l31];
        #pragma unroll
        for (int bb = 0; bb < 2; ++bb){
            float s0[2];
            #pragma unroll
            for (int nt = 0; nt < 2; ++nt){
                float a = 0.f;
                #pragma unroll
                for (int mt = 0; mt < 2; ++mt)
                    #pragma unroll
                    for (int r = 0; r < 16; ++r)
                        a += gelu_fast(acc[bb][mt][nt][r] * INV256 + bvn[nt]);
                s0[nt] = a;
            }
            #pragma unroll
            for (int nt = 0; nt < 2; ++nt) s0[nt] += __shfl_xor(s0[nt], 32);
            if (hi == 0){
                #pragma unroll
                for (int nt = 0; nt < 2; ++nt)
                    pooled[(size_t)(b0 + bb) * 256 + ((w2 + nt) << 5) + l31] = f2bf(s0[nt] * (1.0f / 64.0f));
            }
        }
    }
}

// ---------------- Kernel 2a: heads stages A-C, 16 batches/block ----------------
#define AS 264

__global__ __launch_bounds__(256) void heads_a_kernel(
    const unsigned short* __restrict__ pooled,
    const float* __restrict__ proj_b, const float* __restrict__ val_b1,
    const float* __restrict__ pos_b1, const float* __restrict__ res_b1,
    const float* __restrict__ val_b2, const float* __restrict__ pos_b2,
    const float* __restrict__ mix_b,
    const unsigned short* __restrict__ pk,
    unsigned short* __restrict__ rh, float* __restrict__ meta,
    float* __restrict__ accums)
{
    __shared__ unsigned short pb [16 * AS];
    __shared__ unsigned short eb [16 * AS];
    __shared__ unsigned short vb [16 * AS];
    __shared__ unsigned short phb[16 * AS];
    __shared__ unsigned short rhb[16 * AS];
    __shared__ float av [16 * 132];
    __shared__ float avs[16 * 132];
    __shared__ float psort[16][4];
    __shared__ int   rank [16][4];
    __shared__ float qsh  [16][2];
    __shared__ float mlsh [16][2];
    __shared__ float sposh[16][4];

    const int tid  = threadIdx.x;
    const int b0   = blockIdx.x * 16;
    const int w    = tid >> 6;
    const int lane = tid & 63;
    const int l15  = lane & 15;
    const int q    = lane >> 4;
    const int q8   = q << 3;
    const int q4   = q << 2;

    {
        int g = tid >> 4, seg = tid & 15;
        const unsigned short* ps = pooled + ((size_t)(b0 + g) << 8) + (seg << 4);
        bf16x8 a0 = *(const bf16x8*)ps;
        bf16x8 a1 = *(const bf16x8*)(ps + 8);
        *(bf16x8*)&pb[g * AS + (seg << 4)]     = a0;
        *(bf16x8*)&pb[g * AS + (seg << 4) + 8] = a1;
    }
    __syncthreads();

#define HGEMM256(ASRC, GOFF, BIAS, DST) \
    { f32x4 hacc[4]; \
      _Pragma("unroll") for (int nt = 0; nt < 4; ++nt) hacc[nt] = (f32x4){0.f,0.f,0.f,0.f}; \
      _Pragma("unroll") for (int kk = 0; kk < 8; ++kk){ \
          bf16x8 af = *(const bf16x8*)&(ASRC)[l15 * AS + (kk << 5) + q8]; \
          _Pragma("unroll") for (int nt = 0; nt < 4; ++nt){ \
              bf16x8 bfr = *(const bf16x8*)(pk + (GOFF) + (size_t)((((kk << 4) + (w << 2) + nt) << 6) + lane) * 8); \
              hacc[nt] = __builtin_amdgcn_mfma_f32_16x16x32_bf16(af, bfr, hacc[nt], 0, 0, 0); } } \
      _Pragma("unroll") for (int nt = 0; nt < 4; ++nt){ \
          int n = (w << 6) + (nt << 4) + l15; \
          float bv = (BIAS)[n]; \
          _Pragma("unroll") for (int r = 0; r < 4; ++r) \
              (DST)[(q4 + r) * AS + n] = f2bf(gelu_fast(hacc[nt][r] + bv)); } }

    HGEMM256(pb, O_PROJ, proj_b, eb);
    __syncthreads();

    HGEMM256(eb, O_VAL1, val_b1, vb);
    HGEMM256(eb, O_POS1, pos_b1, phb);
    HGEMM256(eb, O_RES1, res_b1, rhb);
    __syncthreads();

    {
        f32x4 acc2[2];
        #pragma unroll
        for (int nt = 0; nt < 2; ++nt) acc2[nt] = (f32x4){0.f,0.f,0.f,0.f};
        #pragma unroll
        for (int kk = 0; kk < 8; ++kk){
            bf16x8 af = *(const bf16x8*)&vb[l15 * AS + (kk << 5) + q8];
            #pragma unroll
            for (int nt = 0; nt < 2; ++nt){
                bf16x8 bfr = *(const bf16x8*)(pk + O_VAL2 + (size_t)(((kk*8 + w*2 + nt) << 6) + lane) * 8);
                acc2[nt] = __builtin_amdgcn_mfma_f32_16x16x32_bf16(af, bfr, acc2[nt], 0, 0, 0);
            }
        }
        #pragma unroll
        for (int nt = 0; nt < 2; ++nt){
            int j = (w << 5) + (nt << 4) + l15;
            float bv = val_b2[j];
            #pragma unroll
            for (int r = 0; r < 4; ++r)
                av[(q4 + r) * 132 + j] = acc2[nt][r] + bv;
        }
    }
    if (w == 0){
        f32x4 accp = (f32x4){0.f,0.f,0.f,0.f};
        #pragma unroll
        for (int kk = 0; kk < 8; ++kk){
            bf16x8 af  = *(const bf16x8*)&phb[l15 * AS + (kk << 5) + q8];
            bf16x8 bfr = *(const bf16x8*)(pk + O_POS2 + (size_t)((kk << 6) + lane) * 8);
            accp = __builtin_amdgcn_mfma_f32_16x16x32_bf16(af, bfr, accp, 0, 0, 0);
        }
        if (l15 < 4){
            float bv = pos_b2[l15];
            #pragma unroll
            for (int r = 0; r < 4; ++r){
                float raw = accp[r] + bv;
                sposh[q4 + r][l15] = 63.0f / (1.0f + __expf(-raw));
            }
        }
    } else if (w == 1){
        f32x4 accm = (f32x4){0.f,0.f,0.f,0.f};
        #pragma unroll
        for (int kk = 0; kk < 8; ++kk){
            bf16x8 af  = *(const bf16x8*)&eb[l15 * AS + (kk << 5) + q8];
            bf16x8 bfr = *(const bf16x8*)(pk + O_MIX + (size_t)((kk << 6) + lane) * 8);
            accm = __builtin_amdgcn_mfma_f32_16x16x32_bf16(af, bfr, accm, 0, 0, 0);
        }
        if (l15 < 2){
            #pragma unroll
            for (int r = 0; r < 4; ++r)
                mlsh[q4 + r][l15] = accm[r] + mix_b[l15];
        }
    }
    __syncthreads();

    if (tid < 16){
        int g = tid;
        float sv[4] = { sposh[g][0], sposh[g][1], sposh[g][2], sposh[g][3] };
        #pragma unroll
        for (int i = 0; i < 4; ++i){
            int r = 0;
            #pragma unroll
            for (int jj = 0; jj < 4; ++jj){
                r += (sv[jj] < sv[i]) ? 1 : 0;
                if (jj < i) r += (sv[jj] == sv[i]) ? 1 : 0;
            }
            rank[g][i] = r;
            psort[g][r] = sv[i];
        }
        psort[g][0] = 0.0f; psort[g][3] = 63.0f;
        float p1 = psort[g][1], p2 = psort[g][2];
        float g1 = p1, g2 = p2 - p1, g3 = 63.0f - p2;
        const float MG = 10.5f;
        float r1 = fmaxf(MG - g1, 0.f), r2 = fmaxf(MG - g2, 0.f), r3 = fmaxf(MG - g3, 0.f);
        float sp = (r1*r1 + r2*r2 + r3*r3) * (1.0f / 3.0f);
        float l0 = mlsh[g][0], l1 = mlsh[g][1];
        float m = fmaxf(l0, l1);
        float e0 = __expf(l0 - m), e1 = __expf(l1 - m);
        float inv = 1.0f / (e0 + e1);
        float q0 = e0 * inv, q1 = e1 * inv;
        qsh[g][0] = q0; qsh[g][1] = q1;
        float entc = q0 * logf(q0 + 1e-8f) + q1 * logf(q1 + 1e-8f);
        atomicAdd(&accums[2], entc);
        atomicAdd(&accums[3], q0);
        atomicAdd(&accums[4], q1);
        atomicAdd(&accums[5], sp);
    }
    __syncthreads();

    #pragma unroll
    for (int u2 = 0; u2 < 8; ++u2){
        int idx2 = tid * 8 + u2;
        int g = idx2 >> 7, j = idx2 & 127;
        avs[g * 132 + rank[g][j >> 5] * 32 + (j & 31)] = av[g * 132 + j];
    }
    __syncthreads();

    {
        int g = tid >> 4, c16 = (tid & 15) << 4;
        bf16x8 a0 = *(const bf16x8*)&rhb[g * AS + c16];
        bf16x8 a1 = *(const bf16x8*)&rhb[g * AS + c16 + 8];
        unsigned short* dst = rh + ((size_t)(b0 + g) << 8) + c16;
        *(bf16x8*)dst       = a0;
        *(bf16x8*)(dst + 8) = a1;
    }
    if (tid < 132){
        for (int g = 0; g < 16; ++g){
            float v;
            if (tid < 128)       v = avs[g * 132 + tid];
            else if (tid == 128) v = psort[g][1];
            else if (tid == 129) v = psort[g][2];
            else if (tid == 130) v = qsh[g][0];
            else                 v = qsh[g][1];
            meta[(size_t)(b0 + g) * 132 + tid] = v;
        }
    }
}

// ---------------- Kernel 2b: residual GEMM + interp + recon/L1 losses ----------------
__global__ __launch_bounds__(256) void resid_loss_kernel(
    const float* __restrict__ A, const unsigned short* __restrict__ rh,
    const float* __restrict__ res_b2, const unsigned short* __restrict__ pk,
    const float* __restrict__ meta, float* __restrict__ accums)
{
    __shared__ float ml[16 * 132];
    __shared__ float wred[4], wred2[4];

    const int tid  = threadIdx.x;
    const int w    = tid >> 6;
    const int lane = tid & 63;
    const int l15  = lane & 15;
    const int q    = lane >> 4;
    const int q8   = q << 3;
    const int q4   = q << 2;
    const int bg   = blockIdx.x >> 2;
    const int cc   = blockIdx.x & 3;
    const int b0   = bg << 4;

    for (int i = tid; i < 16 * 132; i += 256)
        ml[i] = meta[(size_t)b0 * 132 + i];
    __syncthreads();

    f32x4 acc[8];
    #pragma unroll
    for (int nt = 0; nt < 8; ++nt) acc[nt] = (f32x4){0.f,0.f,0.f,0.f};
    #pragma unroll
    for (int kk = 0; kk < 8; ++kk){
        bf16x8 af = *(const bf16x8*)(rh + ((size_t)(b0 + l15) << 8) + (kk << 5) + q8);
        #pragma unroll
        for (int nt = 0; nt < 8; ++nt){
            int ntg = (cc << 5) + (w << 3) + nt;
            bf16x8 bfr = *(const bf16x8*)(pk + O_RES2 + (size_t)((kk << 7) + ntg) * 512 + (lane << 3));
            acc[nt] = __builtin_amdgcn_mfma_f32_16x16x32_bf16(af, bfr, acc[nt], 0, 0, 0);
        }
    }

    float lsq = 0.f, ll1 = 0.f;
    #pragma unroll
    for (int nt = 0; nt < 8; ++nt){
        int e = (cc << 9) + (w << 7) + (nt << 4) + l15;
        float rbv = res_b2[e];
        int t = e >> 5, d = e & 31;
        float tf = (float)t;
        #pragma unroll
        for (int r = 0; r < 4; ++r){
            int g = q4 + r;
            const float* mg = &ml[g * 132];
            float p1 = mg[128], p2 = mg[129], q0 = mg[130], q1 = mg[131];
            float res = acc[nt][r] + rbv;
            int cnt = (p1 <= tf) + (p2 <= tf) + (tf >= 63.0f);
            int idx = cnt < 2 ? cnt : 2;
            float left  = idx == 0 ? 0.0f : (idx == 1 ? p1 : p2);
            float right = idx == 0 ? p1   : (idx == 1 ? p2 : 63.0f);
            float wgt = (tf - left) / (right - left + 1e-8f);
            wgt = fminf(fmaxf(wgt, 0.f), 1.f);
            float vl = mg[idx * 32 + d];
            float vr = mg[idx * 32 + 32 + d];
            float coarse = vl + wgt * (vr - vl);
            float a = A[((size_t)(b0 + g) << 11) + e];
            float fine = coarse + res;
            float recon = q0 * coarse + q1 * fine;
            float dd = recon - a;
            lsq += dd * dd;
            ll1 += fabsf(res);
        }
    }
    #pragma unroll
    for (int off = 32; off > 0; off >>= 1){
        lsq += __shfl_down(lsq, off);
        ll1 += __shfl_down(ll1, off);
    }
    if (lane == 0){ wred[w] = lsq; wred2[w] = ll1; }
    __syncthreads();
    if (tid == 0){
        atomicAdd(&accums[0], wred[0] + wred[1] + wred[2] + wred[3]);
        atomicAdd(&accums[1], wred2[0] + wred2[1] + wred2[2] + wred2[3]);
    }
}

// ---------------- Kernel 3: finalize ----------------
__global__ void finalize_kernel(const float* __restrict__ accums, float* __restrict__ out){
    float rs = accums[0], l1s = accums[1], ents = accums[2];
    float q0s = accums[3], q1s = accums[4], sps = accums[5];
    const float invN = 1.0f / (4096.0f * 2048.0f);
    const float invB = 1.0f / 4096.0f;
    float recon_loss = rs * invN;
    float l1   = l1s * invN;
    float ent  = -ents * invB;
    float mq0  = q0s * invB - 0.5f, mq1 = q1s * invB - 0.5f;
    float balance = mq0*mq0 + mq1*mq1;
    float spacing = sps * invB;
    out[0] = recon_loss + 0.05f*l1 + 0.01f*ent + 0.1f*balance + 0.1f*spacing;
}

extern "C" void kernel_launch(void* const* d_in, const int* in_sizes, int n_in,
                              void* d_out, int out_size, void* d_ws, size_t ws_size,
                              hipStream_t stream)
{
    const float* A      = (const float*)d_in[0];
    const float* W0     = (const float*)d_in[1];
    const float* B0     = (const float*)d_in[2];
    const float* W1     = (const float*)d_in[3];
    const float* B1     = (const float*)d_in[4];
    const float* W2     = (const float*)d_in[5];
    const float* B2     = (const float*)d_in[6];
    const float* proj_w = (const float*)d_in[7];
    const float* proj_b = (const float*)d_in[8];
    const float* val_w1 = (const float*)d_in[9];
    const float* val_b1 = (const float*)d_in[10];
    const float* val_w2 = (const float*)d_in[11];
    const float* val_b2 = (const float*)d_in[12];
    const float* pos_w1 = (const float*)d_in[13];
    const float* pos_b1 = (const float*)d_in[14];
    const float* pos_w2 = (const float*)d_in[15];
    const float* pos_b2 = (const float*)d_in[16];
    const float* res_w1 = (const float*)d_in[17];
    const float* res_b1 = (const float*)d_in[18];
    const float* res_w2 = (const float*)d_in[19];
    const float* res_b2 = (const float*)d_in[20];
    const float* mix_w  = (const float*)d_in[21];
    const float* mix_b  = (const float*)d_in[22];

    char* wsb = (char*)d_ws;
    float* accums = (float*)wsb;
    unsigned short* pooled = (unsigned short*)(wsb + 256);
    unsigned short* pkbuf  = (unsigned short*)(wsb + 256 + 2097152);
    unsigned short* rhbuf  = (unsigned short*)(wsb + 256 + 2097152 + (size_t)PK_TOTAL * 2);
    float* metabuf = (float*)(wsb + 256 + 2097152 + (size_t)PK_TOTAL * 2 + 2097152);
    unsigned char* wq1 = (unsigned char*)(wsb + 256 + 2097152 + (size_t)PK_TOTAL * 2 + 2097152
                                          + (size_t)4096 * 132 * 4);
    unsigned char* wq2 = wq1 + WQ_BYTES;

    hipMemsetAsync(accums, 0, 64 * sizeof(float), stream);

    hipLaunchKernelGGL(pack_weights, dim3((PK_TOTAL + 255) / 256), dim3(256), 0, stream,
                       W0, W1, W2, proj_w, val_w1, pos_w1, res_w1,
                       val_w2, res_w2, pos_w2, mix_w, pkbuf, wq1, wq2);

    hipLaunchKernelGGL(conv_mfma_kernel, dim3(NB / 2), dim3(256), 0, stream,
                       A, B0, B1, B2,
                       pkbuf + O_WP0, wq1, wq2, pooled);

    hipLaunchKernelGGL(heads_a_kernel, dim3(NB / 16), dim3(256), 0, stream,
                       pooled, proj_b, val_b1, pos_b1, res_b1, val_b2, pos_b2, mix_b,
                       pkbuf, rhbuf, metabuf, accums);

    hipLaunchKernelGGL(resid_loss_kernel, dim3(NB / 16 * 4), dim3(256), 0, stream,
                       A, rhbuf, res_b2, pkbuf, metabuf, accums);

    hipLaunchKernelGGL(finalize_kernel, dim3(1), dim3(1), 0, stream,
                       accums, (float*)d_out);
}

// Round 5
// 515.764 us; speedup vs baseline: 1.2148x; 1.0256x over previous
//
#include <hip/hip_runtime.h>

#define NB 4096

typedef __attribute__((ext_vector_type(8)))  __bf16 bf16x8;
typedef __attribute__((ext_vector_type(4)))  float  f32x4;
typedef __attribute__((ext_vector_type(16))) float  f32x16;
typedef long fp8x8;   // 8 x e4m3 bytes in 2 VGPRs

__device__ __forceinline__ float gelu_fast(float x){
    float x2 = x * x;
    float y  = x * (0.79788456f + 0.03567741f * x2);
    float e  = __expf(2.0f * y);
    float t  = 1.0f - 2.0f / (e + 1.0f);
    return 0.5f * x * (1.0f + t);
}
__device__ __forceinline__ unsigned short f2bf(float x){
    unsigned b = __float_as_uint(x);
    b += 0x7fffu + ((b >> 16) & 1u);
    return (unsigned short)(b >> 16);
}
__device__ __forceinline__ unsigned char f2fp8(float x){
    int p = __builtin_amdgcn_cvt_pk_fp8_f32(x, x, 0, false);
    return (unsigned char)(p & 0xff);
}

// ---------------- pack offsets (elements) ----------------
#define O_WP0  0
#define O_WP1  40960
#define O_WP2  368640
#define O_PROJ 696320
#define O_VAL1 761856
#define O_POS1 827392
#define O_RES1 892928
#define O_VAL2 958464
#define O_RES2 991232
#define O_POS2 1515520
#define O_MIX  1519616
#define PK_TOTAL 1523712

#define WQ_BYTES 327680   // 256*1280 fp8 bytes per conv layer

__device__ __forceinline__ unsigned short pack_std_elem(const float* W, int N, int t){
    int j = t & 7, lane = (t >> 3) & 63, rest = t >> 9;
    int ntcnt = N >> 4;
    int nt = rest % ntcnt, kk = rest / ntcnt;
    int n = nt*16 + (lane & 15), k = kk*32 + ((lane >> 4) << 3) + j;
    return f2bf(W[k * N + n]);
}
__device__ __forceinline__ unsigned short pack_pad_elem(const float* W, int Nreal, int t){
    int j = t & 7, lane = (t >> 3) & 63, kk = t >> 9;
    int n = lane & 15, k = kk*32 + ((lane >> 4) << 3) + j;
    return (n < Nreal) ? f2bf(W[k * Nreal + n]) : (unsigned short)0;
}
// fp8 conv pack: byte idx t -> j=t&7, lane=(t>>3)&63, ntg=(t>>9)&7, S=t>>12 (0..79)
// n = ntg*32+(lane&31); tap=S>>4; ci=(S&15)*16+(lane>>5)*8+j; value = W[n][ci][tap]*32
__device__ __forceinline__ unsigned char pack_fp8_elem(const float* W, int t){
    int j = t & 7, lane = (t >> 3) & 63, ntg = (t >> 9) & 7, S = t >> 12;
    int n = ntg*32 + (lane & 31);
    int tap = S >> 4, ci = ((S & 15) << 4) + ((lane >> 5) << 3) + j;
    return f2fp8(W[n*1280 + ci*5 + tap] * 32.0f);
}

__global__ __launch_bounds__(256) void pack_weights(
    const float* __restrict__ W0, const float* __restrict__ W1, const float* __restrict__ W2,
    const float* __restrict__ proj_w, const float* __restrict__ val_w1,
    const float* __restrict__ pos_w1, const float* __restrict__ res_w1,
    const float* __restrict__ val_w2, const float* __restrict__ res_w2,
    const float* __restrict__ pos_w2, const float* __restrict__ mix_w,
    unsigned short* __restrict__ pk,
    unsigned char* __restrict__ wq1, unsigned char* __restrict__ wq2)
{
    int idx = blockIdx.x * 256 + threadIdx.x;
    if (idx >= PK_TOTAL) return;
    if (idx < O_WP1){
        int t = idx;
        int j = t & 7, lane = (t >> 3) & 63, nt = (t >> 9) & 7, s = t >> 12;   // s 0..9
        int co = nt*32 + (lane & 31);
        int tap = s >> 1, ci = ((s & 1) << 4) + ((lane >> 5) << 3) + j;
        pk[idx] = f2bf(W0[co*160 + ci*5 + tap]);
    } else if (idx < O_WP2){
        wq1[idx - O_WP1] = pack_fp8_elem(W1, idx - O_WP1);
    } else if (idx < O_PROJ){
        wq2[idx - O_WP2] = pack_fp8_elem(W2, idx - O_WP2);
    }
    else if (idx < O_VAL1) pk[idx] = pack_std_elem(proj_w, 256, idx - O_PROJ);
    else if (idx < O_POS1) pk[idx] = pack_std_elem(val_w1, 256, idx - O_VAL1);
    else if (idx < O_RES1) pk[idx] = pack_std_elem(pos_w1, 256, idx - O_POS1);
    else if (idx < O_VAL2) pk[idx] = pack_std_elem(res_w1, 256, idx - O_RES1);
    else if (idx < O_RES2) pk[idx] = pack_std_elem(val_w2, 128, idx - O_VAL2);
    else if (idx < O_POS2) pk[idx] = pack_std_elem(res_w2, 2048, idx - O_RES2);
    else if (idx < O_MIX)  pk[idx] = pack_pad_elem(pos_w2, 4, idx - O_POS2);
    else                   pk[idx] = pack_pad_elem(mix_w, 2, idx - O_MIX);
}

// ---------------- Kernel 1: fp8 conv, 512 thr (8 waves, 1 col-group each), 2 blk/CU ----------------
// acc = [2 batch][2 mt] f32x16 = 64 regs/lane -> 64 AGPR + ~60 arch fits 128 (4 waves/SIMD).
// LDS: 2*ht8 (35904) + 2*xt (10880) = 46784 B -> 2 blocks/CU = 16 waves/CU.
#define HT8_S 264
#define XT_S 40
#define INV256 0.00390625f

__global__ __launch_bounds__(512, 4) void conv_mfma_kernel(
    const float* __restrict__ A,
    const float* __restrict__ B0, const float* __restrict__ B1, const float* __restrict__ B2,
    const unsigned short* __restrict__ wp0,
    const unsigned char* __restrict__ wq1, const unsigned char* __restrict__ wq2,
    unsigned short* __restrict__ pooled)
{
    __shared__ __align__(16) unsigned short xt[2][68 * XT_S];
    __shared__ __align__(16) unsigned char  ht8[2][68 * HT8_S];

    const int tid  = threadIdx.x;
    const int b0   = blockIdx.x * 2;
    const int w    = tid >> 6;        // 0..7: 32-col output group
    const int lane = tid & 63;
    const int l31  = lane & 31;
    const int hi   = lane >> 5;
    const int hi8  = hi << 3;
    const int w32  = w << 5;

    // zero halo rows (taps reach rows 0,1,66,67)
    for (int i = tid; i < 4 * HT8_S; i += 512){
        int r = i / HT8_S, c = i - r * HT8_S;
        int rr = (r < 2 ? r : r + 64);
        ht8[0][rr * HT8_S + c] = 0;
        ht8[1][rr * HT8_S + c] = 0;
    }
    if (tid < 256){
        int bbuf = tid >> 7, i = tid & 127;
        int r = i >> 5, c = i & 31;
        int rr = (r < 2 ? r : r + 64);
        xt[bbuf][rr * XT_S + c] = 0;
    }
    // pack input: 512 threads cover both batches
    {
        int bb = tid >> 8, tt = tid & 255;
        const float* Ab = A + (size_t)(b0 + bb) * 2048;
        int e0 = tt << 3;
        int t = e0 >> 5, c = e0 & 31;
        const float4* p = (const float4*)(Ab + e0);
        float4 v0 = p[0], v1 = p[1];
        union { unsigned short u[8]; bf16x8 v; } pkv;
        pkv.u[0]=f2bf(v0.x); pkv.u[1]=f2bf(v0.y); pkv.u[2]=f2bf(v0.z); pkv.u[3]=f2bf(v0.w);
        pkv.u[4]=f2bf(v1.x); pkv.u[5]=f2bf(v1.y); pkv.u[6]=f2bf(v1.z); pkv.u[7]=f2bf(v1.w);
        *(bf16x8*)&xt[bb][(t + 2) * XT_S + c] = pkv.v;
    }
    __syncthreads();

    f32x16 acc[2][2];   // [batch][mt]

#define ZEROALL \
    { _Pragma("unroll") for (int bb = 0; bb < 2; ++bb) \
      _Pragma("unroll") for (int mt = 0; mt < 2; ++mt) \
      _Pragma("unroll") for (int r = 0; r < 16; ++r) acc[bb][mt][r] = 0.f; }

// bf16 conv0 pieces (xt + wp0) — fragment indexing verified R2-R4
#define LOADB0(BUF, S) \
    BUF = *(const bf16x8*)(wp0 + ((size_t)((((S) << 3) + w) << 6) + lane) * 8);
#define LOADAX(BUF, S) \
    { _Pragma("unroll") for (int bb = 0; bb < 2; ++bb) \
      _Pragma("unroll") for (int mt = 0; mt < 2; ++mt) \
          BUF[bb][mt] = *(const bf16x8*)&xt[bb][((mt << 5) + l31 + ((S) >> 1)) * XT_S + (((S) & 1) << 4) + hi8]; }
#define MFX(X_, B_) \
    { _Pragma("unroll") for (int bb = 0; bb < 2; ++bb) \
      _Pragma("unroll") for (int mt = 0; mt < 2; ++mt) \
          acc[bb][mt] = __builtin_amdgcn_mfma_f32_32x32x16_bf16(X_[bb][mt], B_, acc[bb][mt], 0, 0, 0); }

// fp8 pieces (ht8 + wq) — verified R4
#define LOADB8(BUF, S, WQ) \
    BUF = *(const fp8x8*)((WQ) + ((size_t)((((S) << 3) + w) << 6) + lane) * 8);
#define LOADA8(BUF, S) \
    { _Pragma("unroll") for (int bb = 0; bb < 2; ++bb) \
      _Pragma("unroll") for (int mt = 0; mt < 2; ++mt) \
          BUF[bb][mt] = *(const fp8x8*)&ht8[bb][((mt << 5) + l31 + ((S) >> 4)) * HT8_S + (((S) & 15) << 4) + hi8]; }
#define MF8(A_, B_) \
    { _Pragma("unroll") for (int bb = 0; bb < 2; ++bb) \
      _Pragma("unroll") for (int mt = 0; mt < 2; ++mt) \
          acc[bb][mt] = __builtin_amdgcn_mfma_f32_32x32x16_fp8_fp8(A_[bb][mt], B_, acc[bb][mt], 0, 0, 0); }

// C/D: col = lane&31, row = (r&3) + 8*(r>>2) + 4*(lane>>5)  [verified R2-R4]
#define EPI8(BIAS, SC) \
    { float bv = (BIAS)[w32 + l31]; \
      _Pragma("unroll") for (int bb = 0; bb < 2; ++bb) \
      _Pragma("unroll") for (int mt = 0; mt < 2; ++mt) \
      _Pragma("unroll") for (int r = 0; r < 16; ++r){ \
          int row = (mt << 5) + (r & 3) + ((r >> 2) << 3) + (hi << 2) + 2; \
          float v = gelu_fast(acc[bb][mt][r] * (SC) + bv); \
          ht8[bb][row * HT8_S + w32 + l31] = f2fp8(v * 8.0f); } }

// conv1/conv2: 80 K-steps fp8, depth-2 pipeline, B shared across both batches in regs
#define CONV_F8(WQ) \
    { fp8x8 Ba, Bb, Aa[2][2], Ab_[2][2]; \
      LOADB8(Ba, 0, WQ); LOADA8(Aa, 0); \
      LOADB8(Bb, 1, WQ); LOADA8(Ab_, 1); \
      for (int s = 0; s < 76; s += 2){ \
          MF8(Aa, Ba);  LOADB8(Ba, s + 2, WQ); LOADA8(Aa, s + 2); \
          MF8(Ab_, Bb); LOADB8(Bb, s + 3, WQ); LOADA8(Ab_, s + 3); \
      } \
      MF8(Aa, Ba);  LOADB8(Ba, 78, WQ); LOADA8(Aa, 78); \
      MF8(Ab_, Bb); LOADB8(Bb, 79, WQ); LOADA8(Ab_, 79); \
      MF8(Aa, Ba); \
      MF8(Ab_, Bb); }

    // ---- conv0 (bf16, 10 K-steps, both batches concurrently) ----
    ZEROALL;
    {
        bf16x8 Ba, Bb, Xa[2][2], Xb[2][2];
        LOADB0(Ba, 0); LOADAX(Xa, 0);
        LOADB0(Bb, 1); LOADAX(Xb, 1);
        for (int s = 0; s < 6; s += 2){
            MFX(Xa, Ba); LOADB0(Ba, s + 2); LOADAX(Xa, s + 2);
            MFX(Xb, Bb); LOADB0(Bb, s + 3); LOADAX(Xb, s + 3);
        }
        MFX(Xa, Ba); LOADB0(Ba, 8); LOADAX(Xa, 8);
        MFX(Xb, Bb); LOADB0(Bb, 9); LOADAX(Xb, 9);
        MFX(Xa, Ba);
        MFX(Xb, Bb);
    }
    EPI8(B0, 1.0f);
    __syncthreads();

    // ---- conv1 (fp8) ----
    ZEROALL;
    CONV_F8(wq1);
    __syncthreads();
    EPI8(B1, INV256);
    __syncthreads();

    // ---- conv2 (fp8) + mean pool ----
    ZEROALL;
    CONV_F8(wq2);
    {
        float bv = B2[w32 + l31];
        #pragma unroll
        for (int bb = 0; bb < 2; ++bb){
            float a = 0.f;
            #pragma unroll
            for (int mt = 0; mt < 2; ++mt)
                #pragma unroll
                for (int r = 0; r < 16; ++r)
                    a += gelu_fast(acc[bb][mt][r] * INV256 + bv);
            a += __shfl_xor(a, 32);
            if (hi == 0)
                pooled[(size_t)(b0 + bb) * 256 + w32 + l31] = f2bf(a * (1.0f / 64.0f));
        }
    }
}

// ---------------- Kernel 2a: heads stages A-C, 16 batches/block ----------------
#define AS 264

__global__ __launch_bounds__(256) void heads_a_kernel(
    const unsigned short* __restrict__ pooled,
    const float* __restrict__ proj_b, const float* __restrict__ val_b1,
    const float* __restrict__ pos_b1, const float* __restrict__ res_b1,
    const float* __restrict__ val_b2, const float* __restrict__ pos_b2,
    const float* __restrict__ mix_b,
    const unsigned short* __restrict__ pk,
    unsigned short* __restrict__ rh, float* __restrict__ meta,
    float* __restrict__ accums)
{
    __shared__ unsigned short pb [16 * AS];
    __shared__ unsigned short eb [16 * AS];
    __shared__ unsigned short vb [16 * AS];
    __shared__ unsigned short phb[16 * AS];
    __shared__ unsigned short rhb[16 * AS];
    __shared__ float av [16 * 132];
    __shared__ float avs[16 * 132];
    __shared__ float psort[16][4];
    __shared__ int   rank [16][4];
    __shared__ float qsh  [16][2];
    __shared__ float mlsh [16][2];
    __shared__ float sposh[16][4];

    const int tid  = threadIdx.x;
    const int b0   = blockIdx.x * 16;
    const int w    = tid >> 6;
    const int lane = tid & 63;
    const int l15  = lane & 15;
    const int q    = lane >> 4;
    const int q8   = q << 3;
    const int q4   = q << 2;

    {
        int g = tid >> 4, seg = tid & 15;
        const unsigned short* ps = pooled + ((size_t)(b0 + g) << 8) + (seg << 4);
        bf16x8 a0 = *(const bf16x8*)ps;
        bf16x8 a1 = *(const bf16x8*)(ps + 8);
        *(bf16x8*)&pb[g * AS + (seg << 4)]     = a0;
        *(bf16x8*)&pb[g * AS + (seg << 4) + 8] = a1;
    }
    __syncthreads();

#define HGEMM256(ASRC, GOFF, BIAS, DST) \
    { f32x4 hacc[4]; \
      _Pragma("unroll") for (int nt = 0; nt < 4; ++nt) hacc[nt] = (f32x4){0.f,0.f,0.f,0.f}; \
      _Pragma("unroll") for (int kk = 0; kk < 8; ++kk){ \
          bf16x8 af = *(const bf16x8*)&(ASRC)[l15 * AS + (kk << 5) + q8]; \
          _Pragma("unroll") for (int nt = 0; nt < 4; ++nt){ \
              bf16x8 bfr = *(const bf16x8*)(pk + (GOFF) + (size_t)((((kk << 4) + (w << 2) + nt) << 6) + lane) * 8); \
              hacc[nt] = __builtin_amdgcn_mfma_f32_16x16x32_bf16(af, bfr, hacc[nt], 0, 0, 0); } } \
      _Pragma("unroll") for (int nt = 0; nt < 4; ++nt){ \
          int n = (w << 6) + (nt << 4) + l15; \
          float bv = (BIAS)[n]; \
          _Pragma("unroll") for (int r = 0; r < 4; ++r) \
              (DST)[(q4 + r) * AS + n] = f2bf(gelu_fast(hacc[nt][r] + bv)); } }

    HGEMM256(pb, O_PROJ, proj_b, eb);
    __syncthreads();

    HGEMM256(eb, O_VAL1, val_b1, vb);
    HGEMM256(eb, O_POS1, pos_b1, phb);
    HGEMM256(eb, O_RES1, res_b1, rhb);
    __syncthreads();

    {
        f32x4 acc2[2];
        #pragma unroll
        for (int nt = 0; nt < 2; ++nt) acc2[nt] = (f32x4){0.f,0.f,0.f,0.f};
        #pragma unroll
        for (int kk = 0; kk < 8; ++kk){
            bf16x8 af = *(const bf16x8*)&vb[l15 * AS + (kk << 5) + q8];
            #pragma unroll
            for (int nt = 0; nt < 2; ++nt){
                bf16x8 bfr = *(const bf16x8*)(pk + O_VAL2 + (size_t)(((kk*8 + w*2 + nt) << 6) + lane) * 8);
                acc2[nt] = __builtin_amdgcn_mfma_f32_16x16x32_bf16(af, bfr, acc2[nt], 0, 0, 0);
            }
        }
        #pragma unroll
        for (int nt = 0; nt < 2; ++nt){
            int j = (w << 5) + (nt << 4) + l15;
            float bv = val_b2[j];
            #pragma unroll
            for (int r = 0; r < 4; ++r)
                av[(q4 + r) * 132 + j] = acc2[nt][r] + bv;
        }
    }
    if (w == 0){
        f32x4 accp = (f32x4){0.f,0.f,0.f,0.f};
        #pragma unroll
        for (int kk = 0; kk < 8; ++kk){
            bf16x8 af  = *(const bf16x8*)&phb[l15 * AS + (kk << 5) + q8];
            bf16x8 bfr = *(const bf16x8*)(pk + O_POS2 + (size_t)((kk << 6) + lane) * 8);
            accp = __builtin_amdgcn_mfma_f32_16x16x32_bf16(af, bfr, accp, 0, 0, 0);
        }
        if (l15 < 4){
            float bv = pos_b2[l15];
            #pragma unroll
            for (int r = 0; r < 4; ++r){
                float raw = accp[r] + bv;
                sposh[q4 + r][l15] = 63.0f / (1.0f + __expf(-raw));
            }
        }
    } else if (w == 1){
        f32x4 accm = (f32x4){0.f,0.f,0.f,0.f};
        #pragma unroll
        for (int kk = 0; kk < 8; ++kk){
            bf16x8 af  = *(const bf16x8*)&eb[l15 * AS + (kk << 5) + q8];
            bf16x8 bfr = *(const bf16x8*)(pk + O_MIX + (size_t)((kk << 6) + lane) * 8);
            accm = __builtin_amdgcn_mfma_f32_16x16x32_bf16(af, bfr, accm, 0, 0, 0);
        }
        if (l15 < 2){
            #pragma unroll
            for (int r = 0; r < 4; ++r)
                mlsh[q4 + r][l15] = accm[r] + mix_b[l15];
        }
    }
    __syncthreads();

    if (tid < 16){
        int g = tid;
        float sv[4] = { sposh[g][0], sposh[g][1], sposh[g][2], sposh[g][3] };
        #pragma unroll
        for (int i = 0; i < 4; ++i){
            int r = 0;
            #pragma unroll
            for (int jj = 0; jj < 4; ++jj){
                r += (sv[jj] < sv[i]) ? 1 : 0;
                if (jj < i) r += (sv[jj] == sv[i]) ? 1 : 0;
            }
            rank[g][i] = r;
            psort[g][r] = sv[i];
        }
        psort[g][0] = 0.0f; psort[g][3] = 63.0f;
        float p1 = psort[g][1], p2 = psort[g][2];
        float g1 = p1, g2 = p2 - p1, g3 = 63.0f - p2;
        const float MG = 10.5f;
        float r1 = fmaxf(MG - g1, 0.f), r2 = fmaxf(MG - g2, 0.f), r3 = fmaxf(MG - g3, 0.f);
        float sp = (r1*r1 + r2*r2 + r3*r3) * (1.0f / 3.0f);
        float l0 = mlsh[g][0], l1 = mlsh[g][1];
        float m = fmaxf(l0, l1);
        float e0 = __expf(l0 - m), e1 = __expf(l1 - m);
        float inv = 1.0f / (e0 + e1);
        float q0 = e0 * inv, q1 = e1 * inv;
        qsh[g][0] = q0; qsh[g][1] = q1;
        float entc = q0 * logf(q0 + 1e-8f) + q1 * logf(q1 + 1e-8f);
        atomicAdd(&accums[2], entc);
        atomicAdd(&accums[3], q0);
        atomicAdd(&accums[4], q1);
        atomicAdd(&accums[5], sp);
    }
    __syncthreads();

    #pragma unroll
    for (int u2 = 0; u2 < 8; ++u2){
        int idx2 = tid * 8 + u2;
        int g = idx2 >> 7, j = idx2 & 127;
        avs[g * 132 + rank[g][j >> 5] * 32 + (j & 31)] = av[g * 132 + j];
    }
    __syncthreads();

    {
        int g = tid >> 4, c16 = (tid & 15) << 4;
        bf16x8 a0 = *(const bf16x8*)&rhb[g * AS + c16];
        bf16x8 a1 = *(const bf16x8*)&rhb[g * AS + c16 + 8];
        unsigned short* dst = rh + ((size_t)(b0 + g) << 8) + c16;
        *(bf16x8*)dst       = a0;
        *(bf16x8*)(dst + 8) = a1;
    }
    if (tid < 132){
        for (int g = 0; g < 16; ++g){
            float v;
            if (tid < 128)       v = avs[g * 132 + tid];
            else if (tid == 128) v = psort[g][1];
            else if (tid == 129) v = psort[g][2];
            else if (tid == 130) v = qsh[g][0];
            else                 v = qsh[g][1];
            meta[(size_t)(b0 + g) * 132 + tid] = v;
        }
    }
}

// ---------------- Kernel 2b: residual GEMM + interp + recon/L1 losses ----------------
__global__ __launch_bounds__(256) void resid_loss_kernel(
    const float* __restrict__ A, const unsigned short* __restrict__ rh,
    const float* __restrict__ res_b2, const unsigned short* __restrict__ pk,
    const float* __restrict__ meta, float* __restrict__ accums)
{
    __shared__ float ml[16 * 132];
    __shared__ float wred[4], wred2[4];

    const int tid  = threadIdx.x;
    const int w    = tid >> 6;
    const int lane = tid & 63;
    const int l15  = lane & 15;
    const int q    = lane >> 4;
    const int q8   = q << 3;
    const int q4   = q << 2;
    const int bg   = blockIdx.x >> 2;
    const int cc   = blockIdx.x & 3;
    const int b0   = bg << 4;

    for (int i = tid; i < 16 * 132; i += 256)
        ml[i] = meta[(size_t)b0 * 132 + i];
    __syncthreads();

    f32x4 acc[8];
    #pragma unroll
    for (int nt = 0; nt < 8; ++nt) acc[nt] = (f32x4){0.f,0.f,0.f,0.f};
    #pragma unroll
    for (int kk = 0; kk < 8; ++kk){
        bf16x8 af = *(const bf16x8*)(rh + ((size_t)(b0 + l15) << 8) + (kk << 5) + q8);
        #pragma unroll
        for (int nt = 0; nt < 8; ++nt){
            int ntg = (cc << 5) + (w << 3) + nt;
            bf16x8 bfr = *(const bf16x8*)(pk + O_RES2 + (size_t)((kk << 7) + ntg) * 512 + (lane << 3));
            acc[nt] = __builtin_amdgcn_mfma_f32_16x16x32_bf16(af, bfr, acc[nt], 0, 0, 0);
        }
    }

    float lsq = 0.f, ll1 = 0.f;
    #pragma unroll
    for (int nt = 0; nt < 8; ++nt){
        int e = (cc << 9) + (w << 7) + (nt << 4) + l15;
        float rbv = res_b2[e];
        int t = e >> 5, d = e & 31;
        float tf = (float)t;
        #pragma unroll
        for (int r = 0; r < 4; ++r){
            int g = q4 + r;
            const float* mg = &ml[g * 132];
            float p1 = mg[128], p2 = mg[129], q0 = mg[130], q1 = mg[131];
            float res = acc[nt][r] + rbv;
            int cnt = (p1 <= tf) + (p2 <= tf) + (tf >= 63.0f);
            int idx = cnt < 2 ? cnt : 2;
            float left  = idx == 0 ? 0.0f : (idx == 1 ? p1 : p2);
            float right = idx == 0 ? p1   : (idx == 1 ? p2 : 63.0f);
            float wgt = (tf - left) / (right - left + 1e-8f);
            wgt = fminf(fmaxf(wgt, 0.f), 1.f);
            float vl = mg[idx * 32 + d];
            float vr = mg[idx * 32 + 32 + d];
            float coarse = vl + wgt * (vr - vl);
            float a = A[((size_t)(b0 + g) << 11) + e];
            float fine = coarse + res;
            float recon = q0 * coarse + q1 * fine;
            float dd = recon - a;
            lsq += dd * dd;
            ll1 += fabsf(res);
        }
    }
    #pragma unroll
    for (int off = 32; off > 0; off >>= 1){
        lsq += __shfl_down(lsq, off);
        ll1 += __shfl_down(ll1, off);
    }
    if (lane == 0){ wred[w] = lsq; wred2[w] = ll1; }
    __syncthreads();
    if (tid == 0){
        atomicAdd(&accums[0], wred[0] + wred[1] + wred[2] + wred[3]);
        atomicAdd(&accums[1], wred2[0] + wred2[1] + wred2[2] + wred2[3]);
    }
}

// ---------------- Kernel 3: finalize ----------------
__global__ void finalize_kernel(const float* __restrict__ accums, float* __restrict__ out){
    float rs = accums[0], l1s = accums[1], ents = accums[2];
    float q0s = accums[3], q1s = accums[4], sps = accums[5];
    const float invN = 1.0f / (4096.0f * 2048.0f);
    const float invB = 1.0f / 4096.0f;
    float recon_loss = rs * invN;
    float l1   = l1s * invN;
    float ent  = -ents * invB;
    float mq0  = q0s * invB - 0.5f, mq1 = q1s * invB - 0.5f;
    float balance = mq0*mq0 + mq1*mq1;
    float spacing = sps * invB;
    out[0] = recon_loss + 0.05f*l1 + 0.01f*ent + 0.1f*balance + 0.1f*spacing;
}

extern "C" void kernel_launch(void* const* d_in, const int* in_sizes, int n_in,
                              void* d_out, int out_size, void* d_ws, size_t ws_size,
                              hipStream_t stream)
{
    const float* A      = (const float*)d_in[0];
    const float* W0     = (const float*)d_in[1];
    const float* B0     = (const float*)d_in[2];
    const float* W1     = (const float*)d_in[3];
    const float* B1     = (const float*)d_in[4];
    const float* W2     = (const float*)d_in[5];
    const float* B2     = (const float*)d_in[6];
    const float* proj_w = (const float*)d_in[7];
    const float* proj_b = (const float*)d_in[8];
    const float* val_w1 = (const float*)d_in[9];
    const float* val_b1 = (const float*)d_in[10];
    const float* val_w2 = (const float*)d_in[11];
    const float* val_b2 = (const float*)d_in[12];
    const float* pos_w1 = (const float*)d_in[13];
    const float* pos_b1 = (const float*)d_in[14];
    const float* pos_w2 = (const float*)d_in[15];
    const float* pos_b2 = (const float*)d_in[16];
    const float* res_w1 = (const float*)d_in[17];
    const float* res_b1 = (const float*)d_in[18];
    const float* res_w2 = (const float*)d_in[19];
    const float* res_b2 = (const float*)d_in[20];
    const float* mix_w  = (const float*)d_in[21];
    const float* mix_b  = (const float*)d_in[22];

    char* wsb = (char*)d_ws;
    float* accums = (float*)wsb;
    unsigned short* pooled = (unsigned short*)(wsb + 256);
    unsigned short* pkbuf  = (unsigned short*)(wsb + 256 + 2097152);
    unsigned short* rhbuf  = (unsigned short*)(wsb + 256 + 2097152 + (size_t)PK_TOTAL * 2);
    float* metabuf = (float*)(wsb + 256 + 2097152 + (size_t)PK_TOTAL * 2 + 2097152);
    unsigned char* wq1 = (unsigned char*)(wsb + 256 + 2097152 + (size_t)PK_TOTAL * 2 + 2097152
                                          + (size_t)4096 * 132 * 4);
    unsigned char* wq2 = wq1 + WQ_BYTES;

    hipMemsetAsync(accums, 0, 64 * sizeof(float), stream);

    hipLaunchKernelGGL(pack_weights, dim3((PK_TOTAL + 255) / 256), dim3(256), 0, stream,
                       W0, W1, W2, proj_w, val_w1, pos_w1, res_w1,
                       val_w2, res_w2, pos_w2, mix_w, pkbuf, wq1, wq2);

    hipLaunchKernelGGL(conv_mfma_kernel, dim3(NB / 2), dim3(512), 0, stream,
                       A, B0, B1, B2,
                       pkbuf + O_WP0, wq1, wq2, pooled);

    hipLaunchKernelGGL(heads_a_kernel, dim3(NB / 16), dim3(256), 0, stream,
                       pooled, proj_b, val_b1, pos_b1, res_b1, val_b2, pos_b2, mix_b,
                       pkbuf, rhbuf, metabuf, accums);

    hipLaunchKernelGGL(resid_loss_kernel, dim3(NB / 16 * 4), dim3(256), 0, stream,
                       A, rhbuf, res_b2, pkbuf, metabuf, accums);

    hipLaunchKernelGGL(finalize_kernel, dim3(1), dim3(1), 0, stream,
                       accums, (float*)d_out);
}